// Round 13
// baseline (1892.032 us; speedup 1.0000x reference)
//
#include <hip/hip_runtime.h>

typedef __attribute__((ext_vector_type(8))) short short8;
typedef __attribute__((ext_vector_type(4))) float f32x4;

#define DEV static __device__ __forceinline__

DEV unsigned short f2bf(float x) {
  unsigned u = __float_as_uint(x);
  return (unsigned short)((u + 0x7fffu + ((u >> 16) & 1u)) >> 16);
}
DEV float bf2f(unsigned short h) { return __uint_as_float(((unsigned)h) << 16); }
DEV unsigned char q8(float x, float s) {
  float y = fminf(fmaxf(x * s, -127.f), 127.f);
  return (unsigned char)(((int)rintf(y)) & 0xff);
}

#if __has_builtin(__builtin_amdgcn_sdot4)
#define SDOT4(a, b, c) __builtin_amdgcn_sdot4((int)(a), (int)(b), (c), false)
#else
DEV int SDOT4(unsigned a, unsigned b, int c) {
#pragma unroll
  for (int j = 0; j < 4; ++j)
    c += ((int)(a << (24 - 8 * j)) >> 24) * ((int)(b << (24 - 8 * j)) >> 24);
  return c;
}
#endif

DEV int dot16(uint4 a, uint4 b, int acc) {
  acc = SDOT4(a.x, b.x, acc);
  acc = SDOT4(a.y, b.y, acc);
  acc = SDOT4(a.z, b.z, acc);
  acc = SDOT4(a.w, b.w, acc);
  return acc;
}

// agent-scope relaxed atomics: coherent via IF$ (bypass non-coherent per-XCD L2)
DEV float ald_f(const float* p) {
  return __hip_atomic_load(p, __ATOMIC_RELAXED, __HIP_MEMORY_SCOPE_AGENT);
}
DEV void ast_f(float* p, float v) {
  __hip_atomic_store(p, v, __ATOMIC_RELAXED, __HIP_MEMORY_SCOPE_AGENT);
}
DEV unsigned ald_u(const unsigned* p) {
  return __hip_atomic_load(p, __ATOMIC_RELAXED, __HIP_MEMORY_SCOPE_AGENT);
}
DEV void ast_u(unsigned* p, unsigned v) {
  __hip_atomic_store(p, v, __ATOMIC_RELAXED, __HIP_MEMORY_SCOPE_AGENT);
}

// ---------------- prep: stable descending argsort + int outputs ----------------
__global__ void k_prep(const int* __restrict__ cap_len, const int* __restrict__ captions,
                       int* __restrict__ sind, int* __restrict__ dlen, int* __restrict__ emb_rows,
                       float* __restrict__ out_caps, float* __restrict__ out_dlen,
                       float* __restrict__ out_sind) {
  __shared__ int lens[64];
  __shared__ int ssind[64];
  int i = threadIdx.x;
  lens[i] = cap_len[i];
  __syncthreads();
  int li = lens[i];
  int rank = 0;
  for (int j = 0; j < 64; ++j) {
    int lj = lens[j];
    rank += (lj > li || (lj == li && j < i)) ? 1 : 0;
  }
  ssind[rank] = i;
  __syncthreads();
  int b = i;
  int s = ssind[b];
  sind[b] = s;
  int dl = lens[s] - 1;
  dlen[b] = dl;
  out_dlen[b] = (float)dl;
  out_sind[b] = (float)s;
  for (int l = 0; l < 22; ++l) {
    int cv = captions[s * 22 + l];
    out_caps[b * 22 + l] = (float)cv;
    if (l < 21) emb_rows[l * 64 + b] = cv;
  }
}

// ---------------- gather sorted encoder rows -> bf16 ----------------
__global__ __launch_bounds__(256) void k_gather_enc(const float* __restrict__ enc,
                                                    const int* __restrict__ sind,
                                                    unsigned short* __restrict__ dst) {
  int bp = blockIdx.x;  // 0..12543
  int b = bp / 196, p = bp % 196;
  int tx = threadIdx.x;
  const float* src = enc + ((size_t)sind[b] * 196 + p) * 2048 + tx * 8;
  float4 v0 = *(const float4*)src;
  float4 v1 = *(const float4*)(src + 4);
  uint4 o;
  o.x = f2bf(v0.x) | ((unsigned)f2bf(v0.y) << 16);
  o.y = f2bf(v0.z) | ((unsigned)f2bf(v0.w) << 16);
  o.z = f2bf(v1.x) | ((unsigned)f2bf(v1.y) << 16);
  o.w = f2bf(v1.z) | ((unsigned)f2bf(v1.w) << 16);
  *(uint4*)(dst + (size_t)bp * 2048 + tx * 8) = o;
}

// ---- transpose-convert: src f32 [Ks][N] -> dst bf16 rows perm(n) ----
// perm 0: identity. perm 2: prow = (n&511)*4 + (n>>9)  (gate-interleave j*4+g)
__global__ __launch_bounds__(256) void k_tc(const float* __restrict__ src,
                                            unsigned short* __restrict__ dst, int Ks, int N,
                                            int dstStride, int dstOff, int perm) {
  __shared__ float tile[64][65];
  int n0 = blockIdx.x * 64, k0 = blockIdx.y * 64;
  int tx = threadIdx.x & 63, ty = threadIdx.x >> 6;
#pragma unroll
  for (int r = 0; r < 16; ++r) {
    int kr = r * 4 + ty;
    tile[kr][tx] = src[(size_t)(k0 + kr) * N + n0 + tx];
  }
  __syncthreads();
#pragma unroll
  for (int r = 0; r < 16; ++r) {
    int nr = r * 4 + ty;
    int n = n0 + nr;
    int prow = (perm == 2) ? (((n & 511) << 2) | (n >> 9)) : n;
    dst[(size_t)prow * dstStride + dstOff + k0 + tx] = f2bf(tile[tx][nr]);
  }
}

// ---- transpose-convert to int8: src f32 [Ks][N] -> dst int8 [N][Ks] ----
__global__ __launch_bounds__(256) void k_tc8(const float* __restrict__ src,
                                             unsigned char* __restrict__ dst, int Ks, int N,
                                             float scale) {
  __shared__ float tile[64][65];
  int n0 = blockIdx.x * 64, k0 = blockIdx.y * 64;
  int tx = threadIdx.x & 63, ty = threadIdx.x >> 6;
#pragma unroll
  for (int r = 0; r < 16; ++r) {
    int kr = r * 4 + ty;
    tile[kr][tx] = src[(size_t)(k0 + kr) * N + n0 + tx];
  }
  __syncthreads();
#pragma unroll
  for (int r = 0; r < 16; ++r) {
    int nr = r * 4 + ty;
    dst[(size_t)(n0 + nr) * Ks + k0 + tx] = q8(tile[tx][nr], scale);
  }
}

// ---- W_hh [512][2048] f32 -> int4 offset-binary, perm'd cols, [2048][256B] ----
__global__ __launch_bounds__(256) void k_w4(const float* __restrict__ src,
                                            unsigned char* __restrict__ dst) {
  __shared__ float tile[64][65];
  int n0 = blockIdx.x * 64, k0 = blockIdx.y * 64;
  int t = threadIdx.x;
  int tx = t & 63, ty = t >> 6;
#pragma unroll
  for (int r = 0; r < 16; ++r) {
    int kr = r * 4 + ty;
    tile[kr][tx] = src[(size_t)(k0 + kr) * 2048 + n0 + tx];
  }
  __syncthreads();
  int tx2 = t & 31, ty2 = t >> 5;  // byte, col-group
#pragma unroll
  for (int r = 0; r < 8; ++r) {
    int nr = r * 8 + ty2;
    int n = n0 + nr;
    int qlo = (int)rintf(tile[tx2 * 2][nr] * 158.f) + 8;
    int qhi = (int)rintf(tile[tx2 * 2 + 1][nr] * 158.f) + 8;
    qlo = min(max(qlo, 0), 15);
    qhi = min(max(qhi, 0), 15);
    int prow = ((n & 511) << 2) | (n >> 9);
    dst[(size_t)prow * 256 + (k0 >> 1) + tx2] = (unsigned char)(qlo | (qhi << 4));
  }
}

// ---------------- gather embedding rows -> bf16 A [1408][512] (zero pad) ----------------
__global__ __launch_bounds__(256) void k_gather_emb(const float* __restrict__ emb,
                                                    const int* __restrict__ rows,
                                                    unsigned short* __restrict__ dst) {
  int r = blockIdx.x;
  unsigned short* d = dst + (size_t)r * 512;
  int t = threadIdx.x;
  if (r >= 1344) { d[t] = 0; d[t + 256] = 0; return; }
  const float* s = emb + (size_t)rows[r] * 512;
  d[t] = f2bf(s[t]);
  d[t + 256] = f2bf(s[t + 256]);
}

// ---------------- mean over 196 pixels (from sorted bf16 enc) -> bf16 ----------------
__global__ __launch_bounds__(256) void k_meanb(const unsigned short* __restrict__ encb,
                                               unsigned short* __restrict__ meanb) {
  int b = blockIdx.x, e = blockIdx.y * 256 + threadIdx.x;
  const unsigned short* base = encb + (size_t)b * 196 * 2048 + e;
  float s = 0.f;
  for (int p = 0; p < 196; ++p) s += bf2f(base[(size_t)p * 2048]);
  meanb[(size_t)b * 2048 + e] = f2bf(s * (1.0f / 196.0f));
}

__global__ void k_biascat(const float* __restrict__ bh, const float* __restrict__ bc,
                          float* __restrict__ dst) {
  int i = blockIdx.x * 256 + threadIdx.x;  // grid 4
  dst[i] = (i < 512) ? bh[i] : bc[i - 512];
}

// h0 f32 -> hglob[0]
__global__ void k_h0g(const float* __restrict__ hc, float* __restrict__ hglob) {
  int i = blockIdx.x * 256 + threadIdx.x;  // 32768
  int b = i >> 9, j = i & 511;
  hglob[i] = hc[b * 1024 + j];
}

// ---------------- MFMA GEMM: C[M][N] = A[M][K] @ Bt[N][K]^T (+bias) ----------------
// __launch_bounds__(256, 2): 2 blocks/CU min -> VGPR cap 256 -> NO accumulator spill
// (default heuristic targeted 5 blocks/CU via LDS, capping VGPR ~96 and spilling acc).
// Depth-2 register prefetch with STATIC buffers; XCD-chunked swizzle. K % 128 == 0.
// mode 0: f32 out. mode 2: FC epilogue (rows m=b*21+t, contiguous [m][n] + mask).
// mode 5: merged preatt+E2 epilogue: n<512 -> preatt8 int8(scale 32)+bias;
//         n>=512 -> E2T int4 [b][chunk(p>>5)][n-512][16B], nib=rint(v*2.5)+8.
__global__ __launch_bounds__(256, 2) void k_gemm(const unsigned short* __restrict__ A,
                                                 const unsigned short* __restrict__ Bt,
                                                 const float* __restrict__ bias1,
                                                 const float* __restrict__ bias2,
                                                 float* __restrict__ Cf,
                                                 unsigned short* __restrict__ Cb,
                                                 const int* __restrict__ dlen,
                                                 int M, int N, int K, int mode, int Mreal) {
  __shared__ unsigned short As[128 * 64];
  __shared__ unsigned short Bs[128 * 64];
  int t = threadIdx.x;
  int lane = t & 63, w = t >> 6;
  int wm = w >> 1, wn = w & 1;
  // XCD-chunked swizzle (bijective, m204 form)
  int nwg = gridDim.x * gridDim.y;
  int bid = blockIdx.x + gridDim.x * blockIdx.y;
  int swz = bid;
  if (nwg >= 8) {
    int qq = nwg >> 3, rr = nwg & 7;
    int xcd = bid & 7, idx = bid >> 3;
    swz = (xcd < rr ? xcd * (qq + 1) : rr * (qq + 1) + (xcd - rr) * qq) + idx;
  }
  int m0 = (swz % gridDim.x) * 128, n0 = (swz / gridDim.x) * 128;
  f32x4 acc[4][4] = {};
  uint4 ra0[4], rb0[4], ra1[4], rb1[4];

#define LOADREGS(RA, RB, kc)                                                     \
  {                                                                              \
    _Pragma("unroll") for (int r = 0; r < 4; ++r) {                              \
      int row = r * 32 + (t >> 3), ke = (t & 7) * 8;                             \
      RA[r] = *(const uint4*)(A + (size_t)(m0 + row) * K + (kc) + ke);           \
      RB[r] = *(const uint4*)(Bt + (size_t)(n0 + row) * K + (kc) + ke);          \
    }                                                                            \
  }
#define STORELDS(RA, RB)                                                         \
  {                                                                              \
    _Pragma("unroll") for (int r = 0; r < 4; ++r) {                              \
      int row = r * 32 + (t >> 3), cb = (t & 7) * 16;                            \
      int sw = cb ^ ((row & 7) << 4);                                            \
      *(uint4*)((char*)As + row * 128 + sw) = RA[r];                             \
      *(uint4*)((char*)Bs + row * 128 + sw) = RB[r];                             \
    }                                                                            \
  }
#define DOMFMA()                                                                 \
  {                                                                              \
    _Pragma("unroll") for (int ks = 0; ks < 2; ++ks) {                           \
      short8 af[4], bf[4];                                                       \
      _Pragma("unroll") for (int mi = 0; mi < 4; ++mi) {                         \
        int row = wm * 64 + mi * 16 + (lane & 15);                               \
        int kb = (ks * 64 + (lane >> 4) * 16) ^ ((row & 7) << 4);                \
        af[mi] = *(const short8*)((const char*)As + row * 128 + kb);             \
      }                                                                          \
      _Pragma("unroll") for (int ni = 0; ni < 4; ++ni) {                         \
        int row = wn * 64 + ni * 16 + (lane & 15);                               \
        int kb = (ks * 64 + (lane >> 4) * 16) ^ ((row & 7) << 4);                \
        bf[ni] = *(const short8*)((const char*)Bs + row * 128 + kb);             \
      }                                                                          \
      _Pragma("unroll") for (int mi = 0; mi < 4; ++mi)                           \
          _Pragma("unroll") for (int ni = 0; ni < 4; ++ni)                       \
              acc[mi][ni] = __builtin_amdgcn_mfma_f32_16x16x32_bf16(             \
                  af[mi], bf[ni], acc[mi][ni], 0, 0, 0);                         \
    }                                                                            \
  }

  LOADREGS(ra0, rb0, 0);
  LOADREGS(ra1, rb1, 64);
  for (int kc = 0; kc < K; kc += 128) {
    __syncthreads();
    STORELDS(ra0, rb0);
    __syncthreads();
    if (kc + 128 < K) LOADREGS(ra0, rb0, kc + 128);
    DOMFMA();
    __syncthreads();
    STORELDS(ra1, rb1);
    __syncthreads();
    if (kc + 192 < K) LOADREGS(ra1, rb1, kc + 192);
    DOMFMA();
  }
#undef LOADREGS
#undef STORELDS
#undef DOMFMA

  int rbase = (lane >> 4) * 4;
#pragma unroll
  for (int mi = 0; mi < 4; ++mi) {
#pragma unroll
    for (int ni = 0; ni < 4; ++ni) {
      int n = n0 + wn * 64 + ni * 16 + (lane & 15);
      if (mode == 5) {
        if (n < 512) {
          float badd = bias1 ? bias1[n] : 0.f;
#pragma unroll
          for (int r = 0; r < 4; ++r) {
            int m = m0 + wm * 64 + mi * 16 + rbase + r;
            ((unsigned char*)Cb)[(size_t)m * 512 + n] = q8(acc[mi][ni][r] + badd, 32.f);
          }
        } else {
          int cg = n - 512;
          int m = m0 + wm * 64 + mi * 16 + rbase;  // 4 consecutive rows, 196%4==0 -> same b
          int bb = m / 196, p0 = m - bb * 196;
          unsigned pk = 0;
#pragma unroll
          for (int r = 0; r < 4; ++r) {
            int qv = (int)rintf(acc[mi][ni][r] * 2.5f) + 8;
            qv = min(max(qv, 0), 15);
            pk |= (unsigned)qv << (4 * r);
          }
          *(unsigned short*)((unsigned char*)Cf + (size_t)bb * 229376 +
                             (size_t)(p0 >> 5) * 32768 + (size_t)cg * 16 + ((p0 >> 1) & 15)) =
              (unsigned short)pk;
        }
        continue;
      }
      float badd = (bias1 ? bias1[n] : 0.f) + (bias2 ? bias2[n] : 0.f);
#pragma unroll
      for (int r = 0; r < 4; ++r) {
        int m = m0 + wm * 64 + mi * 16 + rbase + r;
        if (m >= Mreal) continue;
        float v = acc[mi][ni][r] + badd;
        if (mode == 0) {
          Cf[(size_t)m * N + n] = v;
        } else {
          // mode 2: m = b*21 + t, output row m is contiguous in out_pred
          int bb = m / 21, tt = m - bb * 21;
          Cf[(size_t)m * 32000 + n] = (tt < dlen[bb]) ? v : 0.f;
        }
      }
    }
  }
}

// -------- persistent decoder: 256 blocks = 4 per batch (gate-col slices), 4-way sibling sync --------
__global__ __launch_bounds__(1024, 1) void k_loop(
    const unsigned char* __restrict__ preatt8, const unsigned char* __restrict__ E2T,
    const unsigned char* __restrict__ WdT8, const unsigned char* __restrict__ Whh4,
    const float* __restrict__ bd, const float* __restrict__ v_att,
    const float* __restrict__ Wbeta, const float* __restrict__ bbeta,
    const float* __restrict__ ge, const int* __restrict__ dlen,
    const float* __restrict__ hc0, float* __restrict__ hglob,
    unsigned short* __restrict__ hall, unsigned* __restrict__ flags) {
  __shared__ __align__(16) unsigned char preattL[100352];  // [196][512] int8 scale 32
  __shared__ __align__(16) float hL[512], rdL[512], rvL[512], bdL[512], wbL[512];
  __shared__ __align__(16) float eldL[200], red1[256], red2[256];
  __shared__ __align__(16) float gp[2][512];  // per-half gate partials (and datt scratch)
  __shared__ __align__(16) unsigned char hq_lin[512];
  __shared__ __align__(16) unsigned char hq_eo[512];  // [0..255]=even k, [256..511]=odd k
  __shared__ __align__(16) unsigned char aqE[112];    // alpha(2i) int8
  __shared__ __align__(16) unsigned char aqO[112];    // alpha(2i+1) int8
  int blk = blockIdx.x;
  int b = blk >> 2, q = blk & 3;
  int t = threadIdx.x;
  int c = t & 511, half = t >> 9;

  // prologue
  {
    const uint4* sp = (const uint4*)(preatt8 + (size_t)b * 100352);
    uint4* dp = (uint4*)preattL;
    for (int i = t; i < 6272; i += 1024) dp[i] = sp[i];
    if (t < 512) {
      rvL[t] = v_att[t] * (1.f / 32.f);
      bdL[t] = bd[t];
      wbL[t] = Wbeta[t];
    }
    if (t >= 98 && t < 112) { aqE[t] = 0; aqO[t] = 0; }
  }
  float creg = (t < 128) ? hc0[b * 1024 + 512 + 128 * q + t] : 0.f;
  int dlb = dlen[b];
  float bb0 = bbeta[0];
  __syncthreads();

  for (int s = 0; s < 21; ++s) {
    // ---- sibling sync: wait all 4 blocks of this batch at step level s ----
    if (t < 4) {
      while (ald_u(&flags[(b * 4 + t) * 16]) < (unsigned)s) __builtin_amdgcn_s_sleep(1);
    }
    __syncthreads();
    // ---- load full h (double-buffered by parity) + pack int8 (scale 100) ----
    if (t < 512) {
      float hv = ald_f(&hglob[(s & 1) * 32768 + b * 512 + t]);
      hL[t] = hv;
      int qv = (int)rintf(fminf(fmaxf(hv * 100.f, -127.f), 127.f));
      hq_lin[t] = (unsigned char)(qv & 0xff);
      hq_eo[((t & 1) << 8) | (t >> 1)] = (unsigned char)(qv & 0xff);
    }
    __syncthreads();
    // ---- reductions: Sh = sum(hq), beta = h.Wbeta + b ----
    if (t < 256) {
      red1[t] = (float)((signed char)hq_lin[t]) + (float)((signed char)hq_lin[t + 256]);
      red2[t] = hL[t] * wbL[t] + hL[t + 256] * wbL[t + 256];
    }
    __syncthreads();
    for (int st = 128; st > 0; st >>= 1) {
      if (t < st) { red1[t] += red1[t + st]; red2[t] += red2[t + st]; }
      __syncthreads();
    }
    float Sh = red1[0];
    float beta = red2[0] + bb0;
    // ---- datt: col c, k-half per thread ----
    {
      const uint4* wp = (const uint4*)(WdT8 + (size_t)c * 512 + half * 256);
      const uint4* hp = (const uint4*)(hq_lin + half * 256);
      int acc = 0;
#pragma unroll 4
      for (int i = 0; i < 16; ++i) acc = dot16(wp[i], hp[i], acc);
      gp[half][c] = (float)acc;
    }
    __syncthreads();
    if (t < 512)
      rdL[t] = 32.f * bdL[t] + (gp[0][t] + gp[1][t]) * (1.f / 6400.f);
    __syncthreads();
    // ---- e for 196 pixels: 8-lane groups ----
    {
      int g = t & 7, grp = t >> 3;
#pragma unroll
      for (int r = 0; r < 2; ++r) {
        int p = r * 128 + grp;
        float acc = 0.f;
        if (p < 196) {
          const unsigned char* pp = preattL + p * 512;
#pragma unroll
          for (int i = 0; i < 8; ++i) {
            int c0 = i * 64 + g * 8;
            uint2 pv = *(const uint2*)(pp + c0);
#pragma unroll
            for (int jj = 0; jj < 4; ++jj) {
              float x0 = (float)((int)(pv.x << (24 - 8 * jj)) >> 24) + rdL[c0 + jj];
              float x1 = (float)((int)(pv.y << (24 - 8 * jj)) >> 24) + rdL[c0 + 4 + jj];
              acc += fmaxf(x0, 0.f) * rvL[c0 + jj] + fmaxf(x1, 0.f) * rvL[c0 + 4 + jj];
            }
          }
        }
        acc += __shfl_xor(acc, 1, 64);
        acc += __shfl_xor(acc, 2, 64);
        acc += __shfl_xor(acc, 4, 64);
        if (g == 0 && p < 196) eldL[p] = acc;
      }
    }
    __syncthreads();
    // ---- softmax ----
    if (t < 256) red1[t] = (t < 196) ? eldL[t] : -3.4e38f;
    __syncthreads();
    for (int st = 128; st > 0; st >>= 1) {
      if (t < st) red1[t] = fmaxf(red1[t], red1[t + st]);
      __syncthreads();
    }
    float mx = red1[0];
    __syncthreads();
    float ex = 0.f;
    if (t < 256) { ex = (t < 196) ? expf(eldL[t] - mx) : 0.f; red1[t] = ex; }
    __syncthreads();
    for (int st = 128; st > 0; st >>= 1) {
      if (t < st) red1[t] += red1[t + st];
      __syncthreads();
    }
    float ssum = red1[0];
    __syncthreads();
    // ---- alpha*beta -> int8 (dynamic scale), even/odd split; Saq = sum(q) ----
    float ab = 0.f;
    if (t < 256) {
      ab = (t < 196) ? ex * (beta / ssum) : 0.f;
      red1[t] = fabsf(ab);
    }
    __syncthreads();
    for (int st = 128; st > 0; st >>= 1) {
      if (t < st) red1[t] = fmaxf(red1[t], red1[t + st]);
      __syncthreads();
    }
    float sa = 127.f / fmaxf(red1[0], 1e-30f);
    int qa = 0;
    if (t < 196) {
      qa = (int)rintf(ab * sa);
      ((t & 1) ? aqO : aqE)[t >> 1] = (unsigned char)(qa & 0xff);
    }
    if (t < 256) red2[t] = (float)qa;
    __syncthreads();
    for (int st = 128; st > 0; st >>= 1) {
      if (t < st) red2[t] += red2[t + st];
      __syncthreads();
    }
    float Saq = red2[0];
    float inv_z = 1.f / (sa * 2.5f);
    __syncthreads();
    // ---- gate dots for slice col 512q+c, split by half ----
    {
      int cg = 512 * q + c;
      int az = 0, ah = 0;
      const unsigned char* ebase = E2T + (size_t)b * 229376 + (size_t)cg * 16;
      const uint4* ae = (const uint4*)aqE;
      const uint4* ao = (const uint4*)aqO;
      int i0 = half ? 4 : 0, i1 = half ? 7 : 4;
      for (int i = i0; i < i1; ++i) {
        uint4 wv = *(const uint4*)(ebase + (size_t)i * 32768);
        uint4 aev = ae[i], aov = ao[i];
        az = SDOT4(wv.x & 0x0F0F0F0Fu, aev.x, az);
        az = SDOT4((wv.x >> 4) & 0x0F0F0F0Fu, aov.x, az);
        az = SDOT4(wv.y & 0x0F0F0F0Fu, aev.y, az);
        az = SDOT4((wv.y >> 4) & 0x0F0F0F0Fu, aov.y, az);
        az = SDOT4(wv.z & 0x0F0F0F0Fu, aev.z, az);
        az = SDOT4((wv.z >> 4) & 0x0F0F0F0Fu, aov.z, az);
        az = SDOT4(wv.w & 0x0F0F0F0Fu, aev.w, az);
        az = SDOT4((wv.w >> 4) & 0x0F0F0F0Fu, aov.w, az);
      }
      const uint4* w0 = (const uint4*)(Whh4 + (size_t)cg * 256);
      const uint4* he = (const uint4*)hq_eo;
      const uint4* ho = (const uint4*)(hq_eo + 256);
#pragma unroll
      for (int i = 8 * half; i < 8 * half + 8; ++i) {
        uint4 wv = w0[i], hev = he[i], hov = ho[i];
        ah = SDOT4(wv.x & 0x0F0F0F0Fu, hev.x, ah);
        ah = SDOT4((wv.x >> 4) & 0x0F0F0F0Fu, hov.x, ah);
        ah = SDOT4(wv.y & 0x0F0F0F0Fu, hev.y, ah);
        ah = SDOT4((wv.y >> 4) & 0x0F0F0F0Fu, hov.y, ah);
        ah = SDOT4(wv.z & 0x0F0F0F0Fu, hev.z, ah);
        ah = SDOT4((wv.z >> 4) & 0x0F0F0F0Fu, hov.z, ah);
        ah = SDOT4(wv.w & 0x0F0F0F0Fu, hev.w, ah);
        ah = SDOT4((wv.w >> 4) & 0x0F0F0F0Fu, hov.w, ah);
      }
      gp[half][c] = (float)az * inv_z + (float)ah * (1.f / 15800.f);
    }
    __syncthreads();
    // ---- LSTM cell for j-slice [128q, 128q+128) ----
    if (t < 128) {
      int j = 128 * q + t;
      float corr = 8.f * Saq * inv_z + 8.f * Sh * (1.f / 15800.f);
      const float* gep = ge + ((size_t)(s * 64 + b)) * 2048;
      float gi = gp[0][4 * t + 0] + gp[1][4 * t + 0] - corr + gep[j];
      float gf = gp[0][4 * t + 1] + gp[1][4 * t + 1] - corr + gep[512 + j];
      float gg = gp[0][4 * t + 2] + gp[1][4 * t + 2] - corr + gep[1024 + j];
      float go = gp[0][4 * t + 3] + gp[1][4 * t + 3] - corr + gep[1536 + j];
      float si = 1.f / (1.f + expf(-gi));
      float sf = 1.f / (1.f + expf(-gf));
      float so = 1.f / (1.f + expf(-go));
      float cn = sf * creg + si * tanhf(gg);
      float hn = so * tanhf(cn);
      bool msk = s < dlb;
      float hnew = msk ? hn : hL[j];
      creg = msk ? cn : creg;
      ast_f(&hglob[((s + 1) & 1) * 32768 + b * 512 + j], hnew);
      // hall layout: [b*21 + s][512]  -> FC output rows are contiguous [b][t][v]
      hall[((size_t)b * 21 + s) * 512 + j] = f2bf(hn);
    }
    __syncthreads();  // drains vmcnt(0): hglob stores at IF$ before flag
    if (t == 0) ast_u(&flags[blk * 16], (unsigned)(s + 1));
  }
}

extern "C" void kernel_launch(void* const* d_in, const int* in_sizes, int n_in,
                              void* d_out, int out_size, void* d_ws, size_t ws_size,
                              hipStream_t stream) {
  (void)in_sizes; (void)n_in; (void)out_size; (void)ws_size;
  const float* enc = (const float*)d_in[0];
  const int* captions = (const int*)d_in[1];
  const int* cap_len = (const int*)d_in[2];
  const float* emb = (const float*)d_in[3];
  const float* We_att = (const float*)d_in[4];
  const float* be_att = (const float*)d_in[5];
  const float* Wd_att = (const float*)d_in[6];
  const float* bd_att = (const float*)d_in[7];
  const float* v_att = (const float*)d_in[8];
  const float* W_beta = (const float*)d_in[10];
  const float* b_beta = (const float*)d_in[11];
  const float* W_ih = (const float*)d_in[12];
  const float* b_ih = (const float*)d_in[13];
  const float* W_hh = (const float*)d_in[14];
  const float* b_hh = (const float*)d_in[15];
  const float* W_init_h = (const float*)d_in[16];
  const float* b_init_h = (const float*)d_in[17];
  const float* W_init_c = (const float*)d_in[18];
  const float* b_init_c = (const float*)d_in[19];
  const float* W_fc = (const float*)d_in[20];
  const float* b_fc = (const float*)d_in[21];

  float* out = (float*)d_out;
  float* out_pred = out;             // 64*21*32000
  float* out_caps = out + 43008000;  // 1408
  float* out_dlen = out + 43009408;  // 64
  float* out_alph = out + 43009472;  // 263424
  float* out_sind = out + 43272896;  // 64

  char* ws = (char*)d_ws;
  size_t off = 0;
  auto alloc = [&](size_t bytes) -> void* {
    off = (off + 255) & ~(size_t)255;
    void* p = ws + off;
    off += bytes;
    return p;
  };
  int* sind = (int*)alloc(64 * 4);
  int* dlen = (int*)alloc(64 * 4);
  int* emb_rows = (int*)alloc(1344 * 4);
  unsigned* flags = (unsigned*)alloc(256 * 16 * 4);
  unsigned short* enc_b = (unsigned short*)alloc((size_t)25690112 * 2);
  unsigned char* preatt8 = (unsigned char*)alloc((size_t)12544 * 512);
  unsigned char* E2T = (unsigned char*)alloc((size_t)64 * 229376);
  unsigned short* Wcomb = (unsigned short*)alloc((size_t)2560 * 2048 * 2);  // [WeattT;Wih2T]
  unsigned short* WihemT = (unsigned short*)alloc((size_t)2048 * 512 * 2);
  unsigned char* Whh4 = (unsigned char*)alloc((size_t)2048 * 256);
  unsigned short* WfcT = (unsigned short*)alloc((size_t)32000 * 512 * 2);
  unsigned short* WinitT = (unsigned short*)alloc((size_t)1024 * 2048 * 2);
  unsigned char* WdT8 = (unsigned char*)alloc((size_t)512 * 512);
  unsigned short* meanb = (unsigned short*)alloc((size_t)128 * 2048 * 2);
  float* binit = (float*)alloc(1024 * 4);
  unsigned short* Aemb_b = (unsigned short*)alloc((size_t)1408 * 512 * 2);
  unsigned short* hall_b = (unsigned short*)alloc((size_t)1408 * 512 * 2);
  float* ge = (float*)alloc((size_t)1408 * 2048 * 4);
  float* hc = (float*)alloc((size_t)128 * 1024 * 4);
  float* hglob = (float*)alloc((size_t)2 * 64 * 512 * 4);

  k_prep<<<1, 64, 0, stream>>>(cap_len, captions, sind, dlen, emb_rows, out_caps, out_dlen, out_sind);
  hipMemsetAsync(out_alph, 0, (size_t)263424 * 4, stream);
  hipMemsetAsync(flags, 0, 256 * 16 * 4, stream);
  hipMemsetAsync(meanb + (size_t)64 * 2048, 0, (size_t)64 * 2048 * 2, stream);

  k_gather_enc<<<12544, 256, 0, stream>>>(enc, sind, enc_b);
  k_tc8<<<dim3(8, 8), 256, 0, stream>>>(Wd_att, WdT8, 512, 512, 2048.f);
  // Wcomb rows 0..511 = We_att^T
  k_tc<<<dim3(8, 32), 256, 0, stream>>>(We_att, Wcomb, 2048, 512, 2048, 0, 0);
  // Wcomb rows 512..2559 = W_ih2^T (gate-interleave perm)
  k_tc<<<dim3(32, 32), 256, 0, stream>>>(W_ih + (size_t)512 * 2048, Wcomb + (size_t)512 * 2048,
                                         2048, 2048, 2048, 0, 2);
  k_tc<<<dim3(32, 8), 256, 0, stream>>>(W_ih, WihemT, 512, 2048, 512, 0, 0);
  k_w4<<<dim3(32, 8), 256, 0, stream>>>(W_hh, Whh4);
  k_tc<<<dim3(500, 8), 256, 0, stream>>>(W_fc, WfcT, 512, 32000, 512, 0, 0);
  k_tc<<<dim3(8, 32), 256, 0, stream>>>(W_init_h, WinitT, 2048, 512, 2048, 0, 0);
  k_tc<<<dim3(8, 32), 256, 0, stream>>>(W_init_c, WinitT + (size_t)512 * 2048, 2048, 512, 2048, 0, 0);
  k_biascat<<<4, 256, 0, stream>>>(b_init_h, b_init_c, binit);
  k_gather_emb<<<1408, 256, 0, stream>>>(emb, emb_rows, Aemb_b);
  k_meanb<<<dim3(64, 8), 256, 0, stream>>>(enc_b, meanb);

  // h0/c0: mean @ WinitT^T -> hc (M=128 pad, N=1024, K=2048)
  k_gemm<<<dim3(1, 8), 256, 0, stream>>>(meanb, WinitT, binit, nullptr, hc, nullptr, nullptr,
                                         128, 1024, 2048, 0, 64);
  k_h0g<<<128, 256, 0, stream>>>(hc, hglob);
  // ge = emb_seq @ W_ih[0:512] + b_ih + b_hh -> f32
  k_gemm<<<dim3(11, 16), 256, 0, stream>>>(Aemb_b, WihemT, b_ih, b_hh, ge, nullptr, nullptr,
                                           1408, 2048, 512, 0, 1344);
  // merged: [preatt | E2] = enc_s @ [WeattT ; Wih2T]^T  (N=2560, one A pass)
  k_gemm<<<dim3(98, 20), 256, 0, stream>>>(enc_b, Wcomb, be_att, nullptr, (float*)E2T,
                                           (unsigned short*)preatt8, nullptr, 12544, 2560, 2048,
                                           5, 12544);
  // the 21-step recurrence: 256 blocks (4 per batch), local sibling sync only
  k_loop<<<256, 1024, 0, stream>>>(preatt8, E2T, WdT8, Whh4, bd_att, v_att, W_beta, b_beta,
                                   ge, dlen, hc, hglob, hall_b, flags);
  // predictions = mask(h_all[b*21+t] @ W_fc + b_fc) -> contiguous [b][t][v]
  k_gemm<<<dim3(11, 250), 256, 0, stream>>>(hall_b, WfcT, b_fc, nullptr, out_pred, nullptr,
                                            dlen, 1408, 32000, 512, 2, 1344);
}

// Round 14
// 849.823 us; speedup vs baseline: 2.2264x; 2.2264x over previous
//
#include <hip/hip_runtime.h>

typedef __attribute__((ext_vector_type(8))) short short8;
typedef __attribute__((ext_vector_type(4))) float f32x4;

#define DEV static __device__ __forceinline__

DEV unsigned short f2bf(float x) {
  unsigned u = __float_as_uint(x);
  return (unsigned short)((u + 0x7fffu + ((u >> 16) & 1u)) >> 16);
}
DEV float bf2f(unsigned short h) { return __uint_as_float(((unsigned)h) << 16); }
DEV unsigned char q8(float x, float s) {
  float y = fminf(fmaxf(x * s, -127.f), 127.f);
  return (unsigned char)(((int)rintf(y)) & 0xff);
}

#if __has_builtin(__builtin_amdgcn_sdot4)
#define SDOT4(a, b, c) __builtin_amdgcn_sdot4((int)(a), (int)(b), (c), false)
#else
DEV int SDOT4(unsigned a, unsigned b, int c) {
#pragma unroll
  for (int j = 0; j < 4; ++j)
    c += ((int)(a << (24 - 8 * j)) >> 24) * ((int)(b << (24 - 8 * j)) >> 24);
  return c;
}
#endif

DEV int dot16(uint4 a, uint4 b, int acc) {
  acc = SDOT4(a.x, b.x, acc);
  acc = SDOT4(a.y, b.y, acc);
  acc = SDOT4(a.z, b.z, acc);
  acc = SDOT4(a.w, b.w, acc);
  return acc;
}

// agent-scope relaxed atomics: coherent via IF$ (bypass non-coherent per-XCD L2)
DEV float ald_f(const float* p) {
  return __hip_atomic_load(p, __ATOMIC_RELAXED, __HIP_MEMORY_SCOPE_AGENT);
}
DEV void ast_f(float* p, float v) {
  __hip_atomic_store(p, v, __ATOMIC_RELAXED, __HIP_MEMORY_SCOPE_AGENT);
}
DEV unsigned ald_u(const unsigned* p) {
  return __hip_atomic_load(p, __ATOMIC_RELAXED, __HIP_MEMORY_SCOPE_AGENT);
}
DEV void ast_u(unsigned* p, unsigned v) {
  __hip_atomic_store(p, v, __ATOMIC_RELAXED, __HIP_MEMORY_SCOPE_AGENT);
}

// ---------------- prep: stable descending argsort + int outputs ----------------
__global__ void k_prep(const int* __restrict__ cap_len, const int* __restrict__ captions,
                       int* __restrict__ sind, int* __restrict__ dlen, int* __restrict__ emb_rows,
                       float* __restrict__ out_caps, float* __restrict__ out_dlen,
                       float* __restrict__ out_sind) {
  __shared__ int lens[64];
  __shared__ int ssind[64];
  int i = threadIdx.x;
  lens[i] = cap_len[i];
  __syncthreads();
  int li = lens[i];
  int rank = 0;
  for (int j = 0; j < 64; ++j) {
    int lj = lens[j];
    rank += (lj > li || (lj == li && j < i)) ? 1 : 0;
  }
  ssind[rank] = i;
  __syncthreads();
  int b = i;
  int s = ssind[b];
  sind[b] = s;
  int dl = lens[s] - 1;
  dlen[b] = dl;
  out_dlen[b] = (float)dl;
  out_sind[b] = (float)s;
  for (int l = 0; l < 22; ++l) {
    int cv = captions[s * 22 + l];
    out_caps[b * 22 + l] = (float)cv;
    if (l < 21) emb_rows[l * 64 + b] = cv;
  }
}

// ---------------- gather sorted encoder rows -> bf16 ----------------
__global__ __launch_bounds__(256) void k_gather_enc(const float* __restrict__ enc,
                                                    const int* __restrict__ sind,
                                                    unsigned short* __restrict__ dst) {
  int bp = blockIdx.x;  // 0..12543
  int b = bp / 196, p = bp % 196;
  int tx = threadIdx.x;
  const float* src = enc + ((size_t)sind[b] * 196 + p) * 2048 + tx * 8;
  float4 v0 = *(const float4*)src;
  float4 v1 = *(const float4*)(src + 4);
  uint4 o;
  o.x = f2bf(v0.x) | ((unsigned)f2bf(v0.y) << 16);
  o.y = f2bf(v0.z) | ((unsigned)f2bf(v0.w) << 16);
  o.z = f2bf(v1.x) | ((unsigned)f2bf(v1.y) << 16);
  o.w = f2bf(v1.z) | ((unsigned)f2bf(v1.w) << 16);
  *(uint4*)(dst + (size_t)bp * 2048 + tx * 8) = o;
}

// ---- transpose-convert: src f32 [Ks][N] -> dst bf16 rows perm(n) ----
// perm 0: identity. perm 2: prow = (n&511)*4 + (n>>9)  (gate-interleave j*4+g)
__global__ __launch_bounds__(256) void k_tc(const float* __restrict__ src,
                                            unsigned short* __restrict__ dst, int Ks, int N,
                                            int dstStride, int dstOff, int perm) {
  __shared__ float tile[64][65];
  int n0 = blockIdx.x * 64, k0 = blockIdx.y * 64;
  int tx = threadIdx.x & 63, ty = threadIdx.x >> 6;
#pragma unroll
  for (int r = 0; r < 16; ++r) {
    int kr = r * 4 + ty;
    tile[kr][tx] = src[(size_t)(k0 + kr) * N + n0 + tx];
  }
  __syncthreads();
#pragma unroll
  for (int r = 0; r < 16; ++r) {
    int nr = r * 4 + ty;
    int n = n0 + nr;
    int prow = (perm == 2) ? (((n & 511) << 2) | (n >> 9)) : n;
    dst[(size_t)prow * dstStride + dstOff + k0 + tx] = f2bf(tile[tx][nr]);
  }
}

// ---- transpose-convert to int8: src f32 [Ks][N] -> dst int8 [N][Ks] ----
__global__ __launch_bounds__(256) void k_tc8(const float* __restrict__ src,
                                             unsigned char* __restrict__ dst, int Ks, int N,
                                             float scale) {
  __shared__ float tile[64][65];
  int n0 = blockIdx.x * 64, k0 = blockIdx.y * 64;
  int tx = threadIdx.x & 63, ty = threadIdx.x >> 6;
#pragma unroll
  for (int r = 0; r < 16; ++r) {
    int kr = r * 4 + ty;
    tile[kr][tx] = src[(size_t)(k0 + kr) * N + n0 + tx];
  }
  __syncthreads();
#pragma unroll
  for (int r = 0; r < 16; ++r) {
    int nr = r * 4 + ty;
    dst[(size_t)(n0 + nr) * Ks + k0 + tx] = q8(tile[tx][nr], scale);
  }
}

// ---- W_hh [512][2048] f32 -> int4 offset-binary, perm'd cols, [2048][256B] ----
__global__ __launch_bounds__(256) void k_w4(const float* __restrict__ src,
                                            unsigned char* __restrict__ dst) {
  __shared__ float tile[64][65];
  int n0 = blockIdx.x * 64, k0 = blockIdx.y * 64;
  int t = threadIdx.x;
  int tx = t & 63, ty = t >> 6;
#pragma unroll
  for (int r = 0; r < 16; ++r) {
    int kr = r * 4 + ty;
    tile[kr][tx] = src[(size_t)(k0 + kr) * 2048 + n0 + tx];
  }
  __syncthreads();
  int tx2 = t & 31, ty2 = t >> 5;  // byte, col-group
#pragma unroll
  for (int r = 0; r < 8; ++r) {
    int nr = r * 8 + ty2;
    int n = n0 + nr;
    int qlo = (int)rintf(tile[tx2 * 2][nr] * 158.f) + 8;
    int qhi = (int)rintf(tile[tx2 * 2 + 1][nr] * 158.f) + 8;
    qlo = min(max(qlo, 0), 15);
    qhi = min(max(qhi, 0), 15);
    int prow = ((n & 511) << 2) | (n >> 9);
    dst[(size_t)prow * 256 + (k0 >> 1) + tx2] = (unsigned char)(qlo | (qhi << 4));
  }
}

// ---------------- gather embedding rows -> bf16 A [1408][512] (zero pad) ----------------
__global__ __launch_bounds__(256) void k_gather_emb(const float* __restrict__ emb,
                                                    const int* __restrict__ rows,
                                                    unsigned short* __restrict__ dst) {
  int r = blockIdx.x;
  unsigned short* d = dst + (size_t)r * 512;
  int t = threadIdx.x;
  if (r >= 1344) { d[t] = 0; d[t + 256] = 0; return; }
  const float* s = emb + (size_t)rows[r] * 512;
  d[t] = f2bf(s[t]);
  d[t + 256] = f2bf(s[t + 256]);
}

// ---------------- mean over 196 pixels (from sorted bf16 enc) -> bf16 ----------------
__global__ __launch_bounds__(256) void k_meanb(const unsigned short* __restrict__ encb,
                                               unsigned short* __restrict__ meanb) {
  int b = blockIdx.x, e = blockIdx.y * 256 + threadIdx.x;
  const unsigned short* base = encb + (size_t)b * 196 * 2048 + e;
  float s = 0.f;
  for (int p = 0; p < 196; ++p) s += bf2f(base[(size_t)p * 2048]);
  meanb[(size_t)b * 2048 + e] = f2bf(s * (1.0f / 196.0f));
}

__global__ void k_biascat(const float* __restrict__ bh, const float* __restrict__ bc,
                          float* __restrict__ dst) {
  int i = blockIdx.x * 256 + threadIdx.x;  // grid 4
  dst[i] = (i < 512) ? bh[i] : bc[i - 512];
}

// h0 f32 -> hglob[0]
__global__ void k_h0g(const float* __restrict__ hc, float* __restrict__ hglob) {
  int i = blockIdx.x * 256 + threadIdx.x;  // 32768
  int b = i >> 9, j = i & 511;
  hglob[i] = hc[b * 1024 + j];
}

// ---------------- MFMA GEMM: C[M][N] = A[M][K] @ Bt[N][K]^T (+bias) ----------------
// Staging via global_load_lds width=16 (async DMA, no VGPR round-trip, nothing to
// spill). LDS dest is linear (wave-uniform base + lane*16, rule #21); the XOR
// bank-swizzle is applied on the READ side, with the matching INVERSE swizzle
// pre-applied to the per-lane global SOURCE address (m173 pattern).
// mode 0: f32 out. mode 2: FC epilogue (rows m=b*21+t, contiguous [m][n] + mask).
// mode 5: merged preatt+E2 epilogue: n<512 -> preatt8 int8(scale 32)+bias;
//         n>=512 -> E2T int4 [b][chunk(p>>5)][n-512][16B], nib=rint(v*2.5)+8.
__global__ __launch_bounds__(256) void k_gemm(const unsigned short* __restrict__ A,
                                              const unsigned short* __restrict__ Bt,
                                              const float* __restrict__ bias1,
                                              const float* __restrict__ bias2,
                                              float* __restrict__ Cf,
                                              unsigned short* __restrict__ Cb,
                                              const int* __restrict__ dlen,
                                              int M, int N, int K, int mode, int Mreal) {
  __shared__ unsigned short As[128 * 64];
  __shared__ unsigned short Bs[128 * 64];
  int t = threadIdx.x;
  int lane = t & 63, w = t >> 6;
  int wm = w >> 1, wn = w & 1;
  // XCD-chunked swizzle (bijective, m204 form)
  int nwg = gridDim.x * gridDim.y;
  int bid = blockIdx.x + gridDim.x * blockIdx.y;
  int swz = bid;
  if (nwg >= 8) {
    int qq = nwg >> 3, rr = nwg & 7;
    int xcd = bid & 7, idx = bid >> 3;
    swz = (xcd < rr ? xcd * (qq + 1) : rr * (qq + 1) + (xcd - rr) * qq) + idx;
  }
  int m0 = (swz % gridDim.x) * 128, n0 = (swz / gridDim.x) * 128;
  f32x4 acc[4][4] = {};

  // per-lane staging geometry: chunk = 8 rows of 128B; lane covers row lane>>3,
  // 16B piece (lane&7); inverse-swizzled source column.
  int srow = lane >> 3;
  int scol = (((lane & 7) ^ (lane >> 3)) << 4);  // bytes
  size_t rowbytesA = (size_t)K * 2;

#if __has_builtin(__builtin_amdgcn_global_load_lds)
#define STAGE16(GP, LP)                                                          \
  __builtin_amdgcn_global_load_lds(                                              \
      (const __attribute__((address_space(1))) unsigned int*)(GP),               \
      (__attribute__((address_space(3))) unsigned int*)(LP), 16, 0, 0)
#else
#define STAGE16(GP, LP) { *(uint4*)((char*)(LP) + lane * 16) = *(const uint4*)(GP); }
#endif

#define STAGE(MAT, GBASE)                                                        \
  {                                                                              \
    _Pragma("unroll") for (int r = 0; r < 4; ++r) {                              \
      int chunk = r * 4 + w;                                                     \
      const char* g =                                                            \
          (const char*)(GBASE) + (size_t)(chunk * 8 + srow) * rowbytesA + scol;  \
      char* l = (char*)(MAT) + chunk * 1024;                                     \
      STAGE16(g, l);                                                             \
    }                                                                            \
  }
#define DOMFMA()                                                                 \
  {                                                                              \
    _Pragma("unroll") for (int ks = 0; ks < 2; ++ks) {                           \
      short8 af[4], bf[4];                                                       \
      _Pragma("unroll") for (int mi = 0; mi < 4; ++mi) {                         \
        int row = wm * 64 + mi * 16 + (lane & 15);                               \
        int kb = (ks * 64 + (lane >> 4) * 16) ^ ((row & 7) << 4);                \
        af[mi] = *(const short8*)((const char*)As + row * 128 + kb);             \
      }                                                                          \
      _Pragma("unroll") for (int ni = 0; ni < 4; ++ni) {                         \
        int row = wn * 64 + ni * 16 + (lane & 15);                               \
        int kb = (ks * 64 + (lane >> 4) * 16) ^ ((row & 7) << 4);                \
        bf[ni] = *(const short8*)((const char*)Bs + row * 128 + kb);             \
      }                                                                          \
      _Pragma("unroll") for (int mi = 0; mi < 4; ++mi)                           \
          _Pragma("unroll") for (int ni = 0; ni < 4; ++ni)                       \
              acc[mi][ni] = __builtin_amdgcn_mfma_f32_16x16x32_bf16(             \
                  af[mi], bf[ni], acc[mi][ni], 0, 0, 0);                         \
    }                                                                            \
  }

  const char* Abase = (const char*)(A + (size_t)m0 * K);
  const char* Bbase = (const char*)(Bt + (size_t)n0 * K);
  for (int kc = 0; kc < K; kc += 64) {
    __syncthreads();  // previous tile's LDS reads complete
    STAGE(As, Abase + kc * 2);
    STAGE(Bs, Bbase + kc * 2);
    __syncthreads();  // drains vmcnt(0): staged data visible
    DOMFMA();
  }
#undef STAGE
#undef STAGE16
#undef DOMFMA

  int rbase = (lane >> 4) * 4;
#pragma unroll
  for (int mi = 0; mi < 4; ++mi) {
#pragma unroll
    for (int ni = 0; ni < 4; ++ni) {
      int n = n0 + wn * 64 + ni * 16 + (lane & 15);
      if (mode == 5) {
        if (n < 512) {
          float badd = bias1 ? bias1[n] : 0.f;
#pragma unroll
          for (int r = 0; r < 4; ++r) {
            int m = m0 + wm * 64 + mi * 16 + rbase + r;
            ((unsigned char*)Cb)[(size_t)m * 512 + n] = q8(acc[mi][ni][r] + badd, 32.f);
          }
        } else {
          int cg = n - 512;
          int m = m0 + wm * 64 + mi * 16 + rbase;  // 4 consecutive rows, 196%4==0 -> same b
          int bb = m / 196, p0 = m - bb * 196;
          unsigned pk = 0;
#pragma unroll
          for (int r = 0; r < 4; ++r) {
            int qv = (int)rintf(acc[mi][ni][r] * 2.5f) + 8;
            qv = min(max(qv, 0), 15);
            pk |= (unsigned)qv << (4 * r);
          }
          *(unsigned short*)((unsigned char*)Cf + (size_t)bb * 229376 +
                             (size_t)(p0 >> 5) * 32768 + (size_t)cg * 16 + ((p0 >> 1) & 15)) =
              (unsigned short)pk;
        }
        continue;
      }
      float badd = (bias1 ? bias1[n] : 0.f) + (bias2 ? bias2[n] : 0.f);
#pragma unroll
      for (int r = 0; r < 4; ++r) {
        int m = m0 + wm * 64 + mi * 16 + rbase + r;
        if (m >= Mreal) continue;
        float v = acc[mi][ni][r] + badd;
        if (mode == 0) {
          Cf[(size_t)m * N + n] = v;
        } else {
          // mode 2: m = b*21 + t, output row m is contiguous in out_pred
          int bb = m / 21, tt = m - bb * 21;
          Cf[(size_t)m * 32000 + n] = (tt < dlen[bb]) ? v : 0.f;
        }
      }
    }
  }
}

// -------- persistent decoder: 256 blocks = 4 per batch (gate-col slices), 4-way sibling sync --------
__global__ __launch_bounds__(1024, 1) void k_loop(
    const unsigned char* __restrict__ preatt8, const unsigned char* __restrict__ E2T,
    const unsigned char* __restrict__ WdT8, const unsigned char* __restrict__ Whh4,
    const float* __restrict__ bd, const float* __restrict__ v_att,
    const float* __restrict__ Wbeta, const float* __restrict__ bbeta,
    const float* __restrict__ ge, const int* __restrict__ dlen,
    const float* __restrict__ hc0, float* __restrict__ hglob,
    unsigned short* __restrict__ hall, unsigned* __restrict__ flags) {
  __shared__ __align__(16) unsigned char preattL[100352];  // [196][512] int8 scale 32
  __shared__ __align__(16) float hL[512], rdL[512], rvL[512], bdL[512], wbL[512];
  __shared__ __align__(16) float eldL[200], red1[256], red2[256];
  __shared__ __align__(16) float gp[2][512];  // per-half gate partials (and datt scratch)
  __shared__ __align__(16) unsigned char hq_lin[512];
  __shared__ __align__(16) unsigned char hq_eo[512];  // [0..255]=even k, [256..511]=odd k
  __shared__ __align__(16) unsigned char aqE[112];    // alpha(2i) int8
  __shared__ __align__(16) unsigned char aqO[112];    // alpha(2i+1) int8
  int blk = blockIdx.x;
  int b = blk >> 2, q = blk & 3;
  int t = threadIdx.x;
  int c = t & 511, half = t >> 9;

  // prologue
  {
    const uint4* sp = (const uint4*)(preatt8 + (size_t)b * 100352);
    uint4* dp = (uint4*)preattL;
    for (int i = t; i < 6272; i += 1024) dp[i] = sp[i];
    if (t < 512) {
      rvL[t] = v_att[t] * (1.f / 32.f);
      bdL[t] = bd[t];
      wbL[t] = Wbeta[t];
    }
    if (t >= 98 && t < 112) { aqE[t] = 0; aqO[t] = 0; }
  }
  float creg = (t < 128) ? hc0[b * 1024 + 512 + 128 * q + t] : 0.f;
  int dlb = dlen[b];
  float bb0 = bbeta[0];
  __syncthreads();

  for (int s = 0; s < 21; ++s) {
    // ---- sibling sync: wait all 4 blocks of this batch at step level s ----
    if (t < 4) {
      while (ald_u(&flags[(b * 4 + t) * 16]) < (unsigned)s) __builtin_amdgcn_s_sleep(1);
    }
    __syncthreads();
    // ---- load full h (double-buffered by parity) + pack int8 (scale 100) ----
    if (t < 512) {
      float hv = ald_f(&hglob[(s & 1) * 32768 + b * 512 + t]);
      hL[t] = hv;
      int qv = (int)rintf(fminf(fmaxf(hv * 100.f, -127.f), 127.f));
      hq_lin[t] = (unsigned char)(qv & 0xff);
      hq_eo[((t & 1) << 8) | (t >> 1)] = (unsigned char)(qv & 0xff);
    }
    __syncthreads();
    // ---- reductions: Sh = sum(hq), beta = h.Wbeta + b ----
    if (t < 256) {
      red1[t] = (float)((signed char)hq_lin[t]) + (float)((signed char)hq_lin[t + 256]);
      red2[t] = hL[t] * wbL[t] + hL[t + 256] * wbL[t + 256];
    }
    __syncthreads();
    for (int st = 128; st > 0; st >>= 1) {
      if (t < st) { red1[t] += red1[t + st]; red2[t] += red2[t + st]; }
      __syncthreads();
    }
    float Sh = red1[0];
    float beta = red2[0] + bb0;
    // ---- datt: col c, k-half per thread ----
    {
      const uint4* wp = (const uint4*)(WdT8 + (size_t)c * 512 + half * 256);
      const uint4* hp = (const uint4*)(hq_lin + half * 256);
      int acc = 0;
#pragma unroll 4
      for (int i = 0; i < 16; ++i) acc = dot16(wp[i], hp[i], acc);
      gp[half][c] = (float)acc;
    }
    __syncthreads();
    if (t < 512)
      rdL[t] = 32.f * bdL[t] + (gp[0][t] + gp[1][t]) * (1.f / 6400.f);
    __syncthreads();
    // ---- e for 196 pixels: 8-lane groups ----
    {
      int g = t & 7, grp = t >> 3;
#pragma unroll
      for (int r = 0; r < 2; ++r) {
        int p = r * 128 + grp;
        float acc = 0.f;
        if (p < 196) {
          const unsigned char* pp = preattL + p * 512;
#pragma unroll
          for (int i = 0; i < 8; ++i) {
            int c0 = i * 64 + g * 8;
            uint2 pv = *(const uint2*)(pp + c0);
#pragma unroll
            for (int jj = 0; jj < 4; ++jj) {
              float x0 = (float)((int)(pv.x << (24 - 8 * jj)) >> 24) + rdL[c0 + jj];
              float x1 = (float)((int)(pv.y << (24 - 8 * jj)) >> 24) + rdL[c0 + 4 + jj];
              acc += fmaxf(x0, 0.f) * rvL[c0 + jj] + fmaxf(x1, 0.f) * rvL[c0 + 4 + jj];
            }
          }
        }
        acc += __shfl_xor(acc, 1, 64);
        acc += __shfl_xor(acc, 2, 64);
        acc += __shfl_xor(acc, 4, 64);
        if (g == 0 && p < 196) eldL[p] = acc;
      }
    }
    __syncthreads();
    // ---- softmax ----
    if (t < 256) red1[t] = (t < 196) ? eldL[t] : -3.4e38f;
    __syncthreads();
    for (int st = 128; st > 0; st >>= 1) {
      if (t < st) red1[t] = fmaxf(red1[t], red1[t + st]);
      __syncthreads();
    }
    float mx = red1[0];
    __syncthreads();
    float ex = 0.f;
    if (t < 256) { ex = (t < 196) ? expf(eldL[t] - mx) : 0.f; red1[t] = ex; }
    __syncthreads();
    for (int st = 128; st > 0; st >>= 1) {
      if (t < st) red1[t] += red1[t + st];
      __syncthreads();
    }
    float ssum = red1[0];
    __syncthreads();
    // ---- alpha*beta -> int8 (dynamic scale), even/odd split; Saq = sum(q) ----
    float ab = 0.f;
    if (t < 256) {
      ab = (t < 196) ? ex * (beta / ssum) : 0.f;
      red1[t] = fabsf(ab);
    }
    __syncthreads();
    for (int st = 128; st > 0; st >>= 1) {
      if (t < st) red1[t] = fmaxf(red1[t], red1[t + st]);
      __syncthreads();
    }
    float sa = 127.f / fmaxf(red1[0], 1e-30f);
    int qa = 0;
    if (t < 196) {
      qa = (int)rintf(ab * sa);
      ((t & 1) ? aqO : aqE)[t >> 1] = (unsigned char)(qa & 0xff);
    }
    if (t < 256) red2[t] = (float)qa;
    __syncthreads();
    for (int st = 128; st > 0; st >>= 1) {
      if (t < st) red2[t] += red2[t + st];
      __syncthreads();
    }
    float Saq = red2[0];
    float inv_z = 1.f / (sa * 2.5f);
    __syncthreads();
    // ---- gate dots for slice col 512q+c, split by half ----
    {
      int cg = 512 * q + c;
      int az = 0, ah = 0;
      const unsigned char* ebase = E2T + (size_t)b * 229376 + (size_t)cg * 16;
      const uint4* ae = (const uint4*)aqE;
      const uint4* ao = (const uint4*)aqO;
      int i0 = half ? 4 : 0, i1 = half ? 7 : 4;
      for (int i = i0; i < i1; ++i) {
        uint4 wv = *(const uint4*)(ebase + (size_t)i * 32768);
        uint4 aev = ae[i], aov = ao[i];
        az = SDOT4(wv.x & 0x0F0F0F0Fu, aev.x, az);
        az = SDOT4((wv.x >> 4) & 0x0F0F0F0Fu, aov.x, az);
        az = SDOT4(wv.y & 0x0F0F0F0Fu, aev.y, az);
        az = SDOT4((wv.y >> 4) & 0x0F0F0F0Fu, aov.y, az);
        az = SDOT4(wv.z & 0x0F0F0F0Fu, aev.z, az);
        az = SDOT4((wv.z >> 4) & 0x0F0F0F0Fu, aov.z, az);
        az = SDOT4(wv.w & 0x0F0F0F0Fu, aev.w, az);
        az = SDOT4((wv.w >> 4) & 0x0F0F0F0Fu, aov.w, az);
      }
      const uint4* w0 = (const uint4*)(Whh4 + (size_t)cg * 256);
      const uint4* he = (const uint4*)hq_eo;
      const uint4* ho = (const uint4*)(hq_eo + 256);
#pragma unroll
      for (int i = 8 * half; i < 8 * half + 8; ++i) {
        uint4 wv = w0[i], hev = he[i], hov = ho[i];
        ah = SDOT4(wv.x & 0x0F0F0F0Fu, hev.x, ah);
        ah = SDOT4((wv.x >> 4) & 0x0F0F0F0Fu, hov.x, ah);
        ah = SDOT4(wv.y & 0x0F0F0F0Fu, hev.y, ah);
        ah = SDOT4((wv.y >> 4) & 0x0F0F0F0Fu, hov.y, ah);
        ah = SDOT4(wv.z & 0x0F0F0F0Fu, hev.z, ah);
        ah = SDOT4((wv.z >> 4) & 0x0F0F0F0Fu, hov.z, ah);
        ah = SDOT4(wv.w & 0x0F0F0F0Fu, hev.w, ah);
        ah = SDOT4((wv.w >> 4) & 0x0F0F0F0Fu, hov.w, ah);
      }
      gp[half][c] = (float)az * inv_z + (float)ah * (1.f / 15800.f);
    }
    __syncthreads();
    // ---- LSTM cell for j-slice [128q, 128q+128) ----
    if (t < 128) {
      int j = 128 * q + t;
      float corr = 8.f * Saq * inv_z + 8.f * Sh * (1.f / 15800.f);
      const float* gep = ge + ((size_t)(s * 64 + b)) * 2048;
      float gi = gp[0][4 * t + 0] + gp[1][4 * t + 0] - corr + gep[j];
      float gf = gp[0][4 * t + 1] + gp[1][4 * t + 1] - corr + gep[512 + j];
      float gg = gp[0][4 * t + 2] + gp[1][4 * t + 2] - corr + gep[1024 + j];
      float go = gp[0][4 * t + 3] + gp[1][4 * t + 3] - corr + gep[1536 + j];
      float si = 1.f / (1.f + expf(-gi));
      float sf = 1.f / (1.f + expf(-gf));
      float so = 1.f / (1.f + expf(-go));
      float cn = sf * creg + si * tanhf(gg);
      float hn = so * tanhf(cn);
      bool msk = s < dlb;
      float hnew = msk ? hn : hL[j];
      creg = msk ? cn : creg;
      ast_f(&hglob[((s + 1) & 1) * 32768 + b * 512 + j], hnew);
      // hall layout: [b*21 + s][512]  -> FC output rows are contiguous [b][t][v]
      hall[((size_t)b * 21 + s) * 512 + j] = f2bf(hn);
    }
    __syncthreads();  // drains vmcnt(0): hglob stores at IF$ before flag
    if (t == 0) ast_u(&flags[blk * 16], (unsigned)(s + 1));
  }
}

extern "C" void kernel_launch(void* const* d_in, const int* in_sizes, int n_in,
                              void* d_out, int out_size, void* d_ws, size_t ws_size,
                              hipStream_t stream) {
  (void)in_sizes; (void)n_in; (void)out_size; (void)ws_size;
  const float* enc = (const float*)d_in[0];
  const int* captions = (const int*)d_in[1];
  const int* cap_len = (const int*)d_in[2];
  const float* emb = (const float*)d_in[3];
  const float* We_att = (const float*)d_in[4];
  const float* be_att = (const float*)d_in[5];
  const float* Wd_att = (const float*)d_in[6];
  const float* bd_att = (const float*)d_in[7];
  const float* v_att = (const float*)d_in[8];
  const float* W_beta = (const float*)d_in[10];
  const float* b_beta = (const float*)d_in[11];
  const float* W_ih = (const float*)d_in[12];
  const float* b_ih = (const float*)d_in[13];
  const float* W_hh = (const float*)d_in[14];
  const float* b_hh = (const float*)d_in[15];
  const float* W_init_h = (const float*)d_in[16];
  const float* b_init_h = (const float*)d_in[17];
  const float* W_init_c = (const float*)d_in[18];
  const float* b_init_c = (const float*)d_in[19];
  const float* W_fc = (const float*)d_in[20];
  const float* b_fc = (const float*)d_in[21];

  float* out = (float*)d_out;
  float* out_pred = out;             // 64*21*32000
  float* out_caps = out + 43008000;  // 1408
  float* out_dlen = out + 43009408;  // 64
  float* out_alph = out + 43009472;  // 263424
  float* out_sind = out + 43272896;  // 64

  char* ws = (char*)d_ws;
  size_t off = 0;
  auto alloc = [&](size_t bytes) -> void* {
    off = (off + 255) & ~(size_t)255;
    void* p = ws + off;
    off += bytes;
    return p;
  };
  int* sind = (int*)alloc(64 * 4);
  int* dlen = (int*)alloc(64 * 4);
  int* emb_rows = (int*)alloc(1344 * 4);
  unsigned* flags = (unsigned*)alloc(256 * 16 * 4);
  unsigned short* enc_b = (unsigned short*)alloc((size_t)25690112 * 2);
  unsigned char* preatt8 = (unsigned char*)alloc((size_t)12544 * 512);
  unsigned char* E2T = (unsigned char*)alloc((size_t)64 * 229376);
  unsigned short* Wcomb = (unsigned short*)alloc((size_t)2560 * 2048 * 2);  // [WeattT;Wih2T]
  unsigned short* WihemT = (unsigned short*)alloc((size_t)2048 * 512 * 2);
  unsigned char* Whh4 = (unsigned char*)alloc((size_t)2048 * 256);
  unsigned short* WfcT = (unsigned short*)alloc((size_t)32000 * 512 * 2);
  unsigned short* WinitT = (unsigned short*)alloc((size_t)1024 * 2048 * 2);
  unsigned char* WdT8 = (unsigned char*)alloc((size_t)512 * 512);
  unsigned short* meanb = (unsigned short*)alloc((size_t)128 * 2048 * 2);
  float* binit = (float*)alloc(1024 * 4);
  unsigned short* Aemb_b = (unsigned short*)alloc((size_t)1408 * 512 * 2);
  unsigned short* hall_b = (unsigned short*)alloc((size_t)1408 * 512 * 2);
  float* ge = (float*)alloc((size_t)1408 * 2048 * 4);
  float* hc = (float*)alloc((size_t)128 * 1024 * 4);
  float* hglob = (float*)alloc((size_t)2 * 64 * 512 * 4);

  k_prep<<<1, 64, 0, stream>>>(cap_len, captions, sind, dlen, emb_rows, out_caps, out_dlen, out_sind);
  hipMemsetAsync(out_alph, 0, (size_t)263424 * 4, stream);
  hipMemsetAsync(flags, 0, 256 * 16 * 4, stream);
  hipMemsetAsync(meanb + (size_t)64 * 2048, 0, (size_t)64 * 2048 * 2, stream);

  k_gather_enc<<<12544, 256, 0, stream>>>(enc, sind, enc_b);
  k_tc8<<<dim3(8, 8), 256, 0, stream>>>(Wd_att, WdT8, 512, 512, 2048.f);
  // Wcomb rows 0..511 = We_att^T
  k_tc<<<dim3(8, 32), 256, 0, stream>>>(We_att, Wcomb, 2048, 512, 2048, 0, 0);
  // Wcomb rows 512..2559 = W_ih2^T (gate-interleave perm)
  k_tc<<<dim3(32, 32), 256, 0, stream>>>(W_ih + (size_t)512 * 2048, Wcomb + (size_t)512 * 2048,
                                         2048, 2048, 2048, 0, 2);
  k_tc<<<dim3(32, 8), 256, 0, stream>>>(W_ih, WihemT, 512, 2048, 512, 0, 0);
  k_w4<<<dim3(32, 8), 256, 0, stream>>>(W_hh, Whh4);
  k_tc<<<dim3(500, 8), 256, 0, stream>>>(W_fc, WfcT, 512, 32000, 512, 0, 0);
  k_tc<<<dim3(8, 32), 256, 0, stream>>>(W_init_h, WinitT, 2048, 512, 2048, 0, 0);
  k_tc<<<dim3(8, 32), 256, 0, stream>>>(W_init_c, WinitT + (size_t)512 * 2048, 2048, 512, 2048, 0, 0);
  k_biascat<<<4, 256, 0, stream>>>(b_init_h, b_init_c, binit);
  k_gather_emb<<<1408, 256, 0, stream>>>(emb, emb_rows, Aemb_b);
  k_meanb<<<dim3(64, 8), 256, 0, stream>>>(enc_b, meanb);

  // h0/c0: mean @ WinitT^T -> hc (M=128 pad, N=1024, K=2048)
  k_gemm<<<dim3(1, 8), 256, 0, stream>>>(meanb, WinitT, binit, nullptr, hc, nullptr, nullptr,
                                         128, 1024, 2048, 0, 64);
  k_h0g<<<128, 256, 0, stream>>>(hc, hglob);
  // ge = emb_seq @ W_ih[0:512] + b_ih + b_hh -> f32
  k_gemm<<<dim3(11, 16), 256, 0, stream>>>(Aemb_b, WihemT, b_ih, b_hh, ge, nullptr, nullptr,
                                           1408, 2048, 512, 0, 1344);
  // merged: [preatt | E2] = enc_s @ [WeattT ; Wih2T]^T  (N=2560, one A pass)
  k_gemm<<<dim3(98, 20), 256, 0, stream>>>(enc_b, Wcomb, be_att, nullptr, (float*)E2T,
                                           (unsigned short*)preatt8, nullptr, 12544, 2560, 2048,
                                           5, 12544);
  // the 21-step recurrence: 256 blocks (4 per batch), local sibling sync only
  k_loop<<<256, 1024, 0, stream>>>(preatt8, E2T, WdT8, Whh4, bd_att, v_att, W_beta, b_beta,
                                   ge, dlen, hc, hglob, hall_b, flags);
  // predictions = mask(h_all[b*21+t] @ W_fc + b_fc) -> contiguous [b][t][v]
  k_gemm<<<dim3(11, 250), 256, 0, stream>>>(hall_b, WfcT, b_fc, nullptr, out_pred, nullptr,
                                            dlen, 1408, 32000, 512, 2, 1344);
}

// Round 15
// 848.989 us; speedup vs baseline: 2.2286x; 1.0010x over previous
//
#include <hip/hip_runtime.h>

typedef __attribute__((ext_vector_type(8))) short short8;
typedef __attribute__((ext_vector_type(4))) float f32x4;

#define DEV static __device__ __forceinline__

DEV unsigned short f2bf(float x) {
  unsigned u = __float_as_uint(x);
  return (unsigned short)((u + 0x7fffu + ((u >> 16) & 1u)) >> 16);
}
DEV float bf2f(unsigned short h) { return __uint_as_float(((unsigned)h) << 16); }
DEV unsigned char q8(float x, float s) {
  float y = fminf(fmaxf(x * s, -127.f), 127.f);
  return (unsigned char)(((int)rintf(y)) & 0xff);
}

#if __has_builtin(__builtin_amdgcn_sdot4)
#define SDOT4(a, b, c) __builtin_amdgcn_sdot4((int)(a), (int)(b), (c), false)
#else
DEV int SDOT4(unsigned a, unsigned b, int c) {
#pragma unroll
  for (int j = 0; j < 4; ++j)
    c += ((int)(a << (24 - 8 * j)) >> 24) * ((int)(b << (24 - 8 * j)) >> 24);
  return c;
}
#endif

DEV int dot16(uint4 a, uint4 b, int acc) {
  acc = SDOT4(a.x, b.x, acc);
  acc = SDOT4(a.y, b.y, acc);
  acc = SDOT4(a.z, b.z, acc);
  acc = SDOT4(a.w, b.w, acc);
  return acc;
}

// agent-scope relaxed atomics: coherent via IF$ (bypass non-coherent per-XCD L2)
DEV float ald_f(const float* p) {
  return __hip_atomic_load(p, __ATOMIC_RELAXED, __HIP_MEMORY_SCOPE_AGENT);
}
DEV void ast_f(float* p, float v) {
  __hip_atomic_store(p, v, __ATOMIC_RELAXED, __HIP_MEMORY_SCOPE_AGENT);
}
DEV unsigned ald_u(const unsigned* p) {
  return __hip_atomic_load(p, __ATOMIC_RELAXED, __HIP_MEMORY_SCOPE_AGENT);
}
DEV void ast_u(unsigned* p, unsigned v) {
  __hip_atomic_store(p, v, __ATOMIC_RELAXED, __HIP_MEMORY_SCOPE_AGENT);
}

// ---------------- prep: stable descending argsort + int outputs ----------------
__global__ void k_prep(const int* __restrict__ cap_len, const int* __restrict__ captions,
                       int* __restrict__ sind, int* __restrict__ dlen, int* __restrict__ emb_rows,
                       float* __restrict__ out_caps, float* __restrict__ out_dlen,
                       float* __restrict__ out_sind) {
  __shared__ int lens[64];
  __shared__ int ssind[64];
  int i = threadIdx.x;
  lens[i] = cap_len[i];
  __syncthreads();
  int li = lens[i];
  int rank = 0;
  for (int j = 0; j < 64; ++j) {
    int lj = lens[j];
    rank += (lj > li || (lj == li && j < i)) ? 1 : 0;
  }
  ssind[rank] = i;
  __syncthreads();
  int b = i;
  int s = ssind[b];
  sind[b] = s;
  int dl = lens[s] - 1;
  dlen[b] = dl;
  out_dlen[b] = (float)dl;
  out_sind[b] = (float)s;
  for (int l = 0; l < 22; ++l) {
    int cv = captions[s * 22 + l];
    out_caps[b * 22 + l] = (float)cv;
    if (l < 21) emb_rows[l * 64 + b] = cv;
  }
}

// ---------------- gather sorted encoder rows -> bf16 ----------------
__global__ __launch_bounds__(256) void k_gather_enc(const float* __restrict__ enc,
                                                    const int* __restrict__ sind,
                                                    unsigned short* __restrict__ dst) {
  int bp = blockIdx.x;  // 0..12543
  int b = bp / 196, p = bp % 196;
  int tx = threadIdx.x;
  const float* src = enc + ((size_t)sind[b] * 196 + p) * 2048 + tx * 8;
  float4 v0 = *(const float4*)src;
  float4 v1 = *(const float4*)(src + 4);
  uint4 o;
  o.x = f2bf(v0.x) | ((unsigned)f2bf(v0.y) << 16);
  o.y = f2bf(v0.z) | ((unsigned)f2bf(v0.w) << 16);
  o.z = f2bf(v1.x) | ((unsigned)f2bf(v1.y) << 16);
  o.w = f2bf(v1.z) | ((unsigned)f2bf(v1.w) << 16);
  *(uint4*)(dst + (size_t)bp * 2048 + tx * 8) = o;
}

// ---- transpose-convert: src f32 [Ks][N] -> dst bf16 rows perm(n) ----
// perm 0: identity. perm 2: prow = (n&511)*4 + (n>>9)  (gate-interleave j*4+g)
__global__ __launch_bounds__(256) void k_tc(const float* __restrict__ src,
                                            unsigned short* __restrict__ dst, int Ks, int N,
                                            int dstStride, int dstOff, int perm) {
  __shared__ float tile[64][65];
  int n0 = blockIdx.x * 64, k0 = blockIdx.y * 64;
  int tx = threadIdx.x & 63, ty = threadIdx.x >> 6;
#pragma unroll
  for (int r = 0; r < 16; ++r) {
    int kr = r * 4 + ty;
    tile[kr][tx] = src[(size_t)(k0 + kr) * N + n0 + tx];
  }
  __syncthreads();
#pragma unroll
  for (int r = 0; r < 16; ++r) {
    int nr = r * 4 + ty;
    int n = n0 + nr;
    int prow = (perm == 2) ? (((n & 511) << 2) | (n >> 9)) : n;
    dst[(size_t)prow * dstStride + dstOff + k0 + tx] = f2bf(tile[tx][nr]);
  }
}

// ---- transpose-convert to int8: src f32 [Ks][N] -> dst int8 [N][Ks] ----
__global__ __launch_bounds__(256) void k_tc8(const float* __restrict__ src,
                                             unsigned char* __restrict__ dst, int Ks, int N,
                                             float scale) {
  __shared__ float tile[64][65];
  int n0 = blockIdx.x * 64, k0 = blockIdx.y * 64;
  int tx = threadIdx.x & 63, ty = threadIdx.x >> 6;
#pragma unroll
  for (int r = 0; r < 16; ++r) {
    int kr = r * 4 + ty;
    tile[kr][tx] = src[(size_t)(k0 + kr) * N + n0 + tx];
  }
  __syncthreads();
#pragma unroll
  for (int r = 0; r < 16; ++r) {
    int nr = r * 4 + ty;
    dst[(size_t)(n0 + nr) * Ks + k0 + tx] = q8(tile[tx][nr], scale);
  }
}

// ---- W_hh [512][2048] f32 -> int4 offset-binary, perm'd cols, [2048][256B] ----
__global__ __launch_bounds__(256) void k_w4(const float* __restrict__ src,
                                            unsigned char* __restrict__ dst) {
  __shared__ float tile[64][65];
  int n0 = blockIdx.x * 64, k0 = blockIdx.y * 64;
  int t = threadIdx.x;
  int tx = t & 63, ty = t >> 6;
#pragma unroll
  for (int r = 0; r < 16; ++r) {
    int kr = r * 4 + ty;
    tile[kr][tx] = src[(size_t)(k0 + kr) * 2048 + n0 + tx];
  }
  __syncthreads();
  int tx2 = t & 31, ty2 = t >> 5;  // byte, col-group
#pragma unroll
  for (int r = 0; r < 8; ++r) {
    int nr = r * 8 + ty2;
    int n = n0 + nr;
    int qlo = (int)rintf(tile[tx2 * 2][nr] * 158.f) + 8;
    int qhi = (int)rintf(tile[tx2 * 2 + 1][nr] * 158.f) + 8;
    qlo = min(max(qlo, 0), 15);
    qhi = min(max(qhi, 0), 15);
    int prow = ((n & 511) << 2) | (n >> 9);
    dst[(size_t)prow * 256 + (k0 >> 1) + tx2] = (unsigned char)(qlo | (qhi << 4));
  }
}

// ---------------- gather embedding rows -> bf16 A [1408][512] (zero pad) ----------------
__global__ __launch_bounds__(256) void k_gather_emb(const float* __restrict__ emb,
                                                    const int* __restrict__ rows,
                                                    unsigned short* __restrict__ dst) {
  int r = blockIdx.x;
  unsigned short* d = dst + (size_t)r * 512;
  int t = threadIdx.x;
  if (r >= 1344) { d[t] = 0; d[t + 256] = 0; return; }
  const float* s = emb + (size_t)rows[r] * 512;
  d[t] = f2bf(s[t]);
  d[t + 256] = f2bf(s[t + 256]);
}

// ---------------- mean over 196 pixels (from sorted bf16 enc) -> bf16 ----------------
__global__ __launch_bounds__(256) void k_meanb(const unsigned short* __restrict__ encb,
                                               unsigned short* __restrict__ meanb) {
  int b = blockIdx.x, e = blockIdx.y * 256 + threadIdx.x;
  const unsigned short* base = encb + (size_t)b * 196 * 2048 + e;
  float s = 0.f;
  for (int p = 0; p < 196; ++p) s += bf2f(base[(size_t)p * 2048]);
  meanb[(size_t)b * 2048 + e] = f2bf(s * (1.0f / 196.0f));
}

__global__ void k_biascat(const float* __restrict__ bh, const float* __restrict__ bc,
                          float* __restrict__ dst) {
  int i = blockIdx.x * 256 + threadIdx.x;  // grid 4
  dst[i] = (i < 512) ? bh[i] : bc[i - 512];
}

// h0 f32 -> hglob[0]
__global__ void k_h0g(const float* __restrict__ hc, float* __restrict__ hglob) {
  int i = blockIdx.x * 256 + threadIdx.x;  // 32768
  int b = i >> 9, j = i & 511;
  hglob[i] = hc[b * 1024 + j];
}

// ---------------- MFMA GEMM: C[M][N] = A[M][K] @ Bt[N][K]^T (+bias) ----------------
// Staging via global_load_lds width=16 (async DMA, no VGPR round-trip, nothing to
// spill). LDS dest is linear (wave-uniform base + lane*16, rule #21); the XOR
// bank-swizzle is applied on the READ side, with the matching INVERSE swizzle
// pre-applied to the per-lane global SOURCE address (m173 pattern).
// mode 0: f32 out. mode 2: FC epilogue (rows m=b*21+t, contiguous [m][n] + mask).
// mode 5: merged preatt+E2 epilogue: n<512 -> preatt8 int8(scale 32)+bias;
//         n>=512 -> E2T int4 [b][chunk(p>>5)][n-512][16B], nib=rint(v*2.5)+8.
__global__ __launch_bounds__(256) void k_gemm(const unsigned short* __restrict__ A,
                                              const unsigned short* __restrict__ Bt,
                                              const float* __restrict__ bias1,
                                              const float* __restrict__ bias2,
                                              float* __restrict__ Cf,
                                              unsigned short* __restrict__ Cb,
                                              const int* __restrict__ dlen,
                                              int M, int N, int K, int mode, int Mreal) {
  __shared__ unsigned short As[128 * 64];
  __shared__ unsigned short Bs[128 * 64];
  int t = threadIdx.x;
  int lane = t & 63, w = t >> 6;
  int wm = w >> 1, wn = w & 1;
  // XCD-chunked swizzle (bijective, m204 form)
  int nwg = gridDim.x * gridDim.y;
  int bid = blockIdx.x + gridDim.x * blockIdx.y;
  int swz = bid;
  if (nwg >= 8) {
    int qq = nwg >> 3, rr = nwg & 7;
    int xcd = bid & 7, idx = bid >> 3;
    swz = (xcd < rr ? xcd * (qq + 1) : rr * (qq + 1) + (xcd - rr) * qq) + idx;
  }
  int m0 = (swz % gridDim.x) * 128, n0 = (swz / gridDim.x) * 128;
  f32x4 acc[4][4] = {};

  // per-lane staging geometry: chunk = 8 rows of 128B; lane covers row lane>>3,
  // 16B piece (lane&7); inverse-swizzled source column.
  int srow = lane >> 3;
  int scol = (((lane & 7) ^ (lane >> 3)) << 4);  // bytes
  size_t rowbytesA = (size_t)K * 2;

#if __has_builtin(__builtin_amdgcn_global_load_lds)
#define STAGE16(GP, LP)                                                          \
  __builtin_amdgcn_global_load_lds(                                              \
      (const __attribute__((address_space(1))) unsigned int*)(GP),               \
      (__attribute__((address_space(3))) unsigned int*)(LP), 16, 0, 0)
#else
#define STAGE16(GP, LP) { *(uint4*)((char*)(LP) + lane * 16) = *(const uint4*)(GP); }
#endif

#define STAGE(MAT, GBASE)                                                        \
  {                                                                              \
    _Pragma("unroll") for (int r = 0; r < 4; ++r) {                              \
      int chunk = r * 4 + w;                                                     \
      const char* g =                                                            \
          (const char*)(GBASE) + (size_t)(chunk * 8 + srow) * rowbytesA + scol;  \
      char* l = (char*)(MAT) + chunk * 1024;                                     \
      STAGE16(g, l);                                                             \
    }                                                                            \
  }
#define DOMFMA()                                                                 \
  {                                                                              \
    _Pragma("unroll") for (int ks = 0; ks < 2; ++ks) {                           \
      short8 af[4], bf[4];                                                       \
      _Pragma("unroll") for (int mi = 0; mi < 4; ++mi) {                         \
        int row = wm * 64 + mi * 16 + (lane & 15);                               \
        int kb = (ks * 64 + (lane >> 4) * 16) ^ ((row & 7) << 4);                \
        af[mi] = *(const short8*)((const char*)As + row * 128 + kb);             \
      }                                                                          \
      _Pragma("unroll") for (int ni = 0; ni < 4; ++ni) {                         \
        int row = wn * 64 + ni * 16 + (lane & 15);                               \
        int kb = (ks * 64 + (lane >> 4) * 16) ^ ((row & 7) << 4);                \
        bf[ni] = *(const short8*)((const char*)Bs + row * 128 + kb);             \
      }                                                                          \
      _Pragma("unroll") for (int mi = 0; mi < 4; ++mi)                           \
          _Pragma("unroll") for (int ni = 0; ni < 4; ++ni)                       \
              acc[mi][ni] = __builtin_amdgcn_mfma_f32_16x16x32_bf16(             \
                  af[mi], bf[ni], acc[mi][ni], 0, 0, 0);                         \
    }                                                                            \
  }

  const char* Abase = (const char*)(A + (size_t)m0 * K);
  const char* Bbase = (const char*)(Bt + (size_t)n0 * K);
  for (int kc = 0; kc < K; kc += 64) {
    __syncthreads();  // previous tile's LDS reads complete
    STAGE(As, Abase + kc * 2);
    STAGE(Bs, Bbase + kc * 2);
    __syncthreads();  // drains vmcnt(0): staged data visible
    DOMFMA();
  }
#undef STAGE
#undef STAGE16
#undef DOMFMA

  int rbase = (lane >> 4) * 4;
#pragma unroll
  for (int mi = 0; mi < 4; ++mi) {
#pragma unroll
    for (int ni = 0; ni < 4; ++ni) {
      int n = n0 + wn * 64 + ni * 16 + (lane & 15);
      if (mode == 5) {
        if (n < 512) {
          float badd = bias1 ? bias1[n] : 0.f;
#pragma unroll
          for (int r = 0; r < 4; ++r) {
            int m = m0 + wm * 64 + mi * 16 + rbase + r;
            ((unsigned char*)Cb)[(size_t)m * 512 + n] = q8(acc[mi][ni][r] + badd, 32.f);
          }
        } else {
          int cg = n - 512;
          int m = m0 + wm * 64 + mi * 16 + rbase;  // 4 consecutive rows, 196%4==0 -> same b
          int bb = m / 196, p0 = m - bb * 196;
          unsigned pk = 0;
#pragma unroll
          for (int r = 0; r < 4; ++r) {
            int qv = (int)rintf(acc[mi][ni][r] * 2.5f) + 8;
            qv = min(max(qv, 0), 15);
            pk |= (unsigned)qv << (4 * r);
          }
          *(unsigned short*)((unsigned char*)Cf + (size_t)bb * 229376 +
                             (size_t)(p0 >> 5) * 32768 + (size_t)cg * 16 + ((p0 >> 1) & 15)) =
              (unsigned short)pk;
        }
        continue;
      }
      float badd = (bias1 ? bias1[n] : 0.f) + (bias2 ? bias2[n] : 0.f);
#pragma unroll
      for (int r = 0; r < 4; ++r) {
        int m = m0 + wm * 64 + mi * 16 + rbase + r;
        if (m >= Mreal) continue;
        float v = acc[mi][ni][r] + badd;
        if (mode == 0) {
          Cf[(size_t)m * N + n] = v;
        } else {
          // mode 2: m = b*21 + t, output row m is contiguous in out_pred
          int bb = m / 21, tt = m - bb * 21;
          Cf[(size_t)m * 32000 + n] = (tt < dlen[bb]) ? v : 0.f;
        }
      }
    }
  }
}

// -------- persistent decoder: 256 blocks = 4 per batch (gate-col slices), 4-way sibling sync --------
__global__ __launch_bounds__(1024, 1) void k_loop(
    const unsigned char* __restrict__ preatt8, const unsigned char* __restrict__ E2T,
    const unsigned char* __restrict__ WdT8, const unsigned char* __restrict__ Whh4,
    const float* __restrict__ bd, const float* __restrict__ v_att,
    const float* __restrict__ Wbeta, const float* __restrict__ bbeta,
    const float* __restrict__ ge, const int* __restrict__ dlen,
    const float* __restrict__ hc0, float* __restrict__ hglob,
    unsigned short* __restrict__ hall, unsigned* __restrict__ flags) {
  __shared__ __align__(16) unsigned char preattL[100352];  // [196][512] int8 scale 32
  __shared__ __align__(16) float hL[512], rdL[512], rvL[512], bdL[512], wbL[512];
  __shared__ __align__(16) float eldL[200], red1[256], red2[256];
  __shared__ __align__(16) float gp[2][512];  // per-half gate partials (and datt scratch)
  __shared__ __align__(16) unsigned char hq_lin[512];
  __shared__ __align__(16) unsigned char hq_eo[512];  // [0..255]=even k, [256..511]=odd k
  __shared__ __align__(16) unsigned char aqE[112];    // alpha(2i) int8
  __shared__ __align__(16) unsigned char aqO[112];    // alpha(2i+1) int8
  int blk = blockIdx.x;
  int b = blk >> 2, q = blk & 3;
  int t = threadIdx.x;
  int c = t & 511, half = t >> 9;

  // prologue
  {
    const uint4* sp = (const uint4*)(preatt8 + (size_t)b * 100352);
    uint4* dp = (uint4*)preattL;
    for (int i = t; i < 6272; i += 1024) dp[i] = sp[i];
    if (t < 512) {
      rvL[t] = v_att[t] * (1.f / 32.f);
      bdL[t] = bd[t];
      wbL[t] = Wbeta[t];
    }
    if (t >= 98 && t < 112) { aqE[t] = 0; aqO[t] = 0; }
  }
  float creg = (t < 128) ? hc0[b * 1024 + 512 + 128 * q + t] : 0.f;
  int dlb = dlen[b];
  float bb0 = bbeta[0];
  __syncthreads();

  for (int s = 0; s < 21; ++s) {
    // ---- sibling sync: wait all 4 blocks of this batch at step level s ----
    if (t < 4) {
      while (ald_u(&flags[(b * 4 + t) * 16]) < (unsigned)s) __builtin_amdgcn_s_sleep(1);
    }
    __syncthreads();
    // ---- load full h (double-buffered by parity) + pack int8 (scale 100) ----
    if (t < 512) {
      float hv = ald_f(&hglob[(s & 1) * 32768 + b * 512 + t]);
      hL[t] = hv;
      int qv = (int)rintf(fminf(fmaxf(hv * 100.f, -127.f), 127.f));
      hq_lin[t] = (unsigned char)(qv & 0xff);
      hq_eo[((t & 1) << 8) | (t >> 1)] = (unsigned char)(qv & 0xff);
    }
    __syncthreads();
    // ---- reductions: Sh = sum(hq), beta = h.Wbeta + b ----
    if (t < 256) {
      red1[t] = (float)((signed char)hq_lin[t]) + (float)((signed char)hq_lin[t + 256]);
      red2[t] = hL[t] * wbL[t] + hL[t + 256] * wbL[t + 256];
    }
    __syncthreads();
    for (int st = 128; st > 0; st >>= 1) {
      if (t < st) { red1[t] += red1[t + st]; red2[t] += red2[t + st]; }
      __syncthreads();
    }
    float Sh = red1[0];
    float beta = red2[0] + bb0;
    // ---- datt: col c, k-half per thread ----
    {
      const uint4* wp = (const uint4*)(WdT8 + (size_t)c * 512 + half * 256);
      const uint4* hp = (const uint4*)(hq_lin + half * 256);
      int acc = 0;
#pragma unroll 4
      for (int i = 0; i < 16; ++i) acc = dot16(wp[i], hp[i], acc);
      gp[half][c] = (float)acc;
    }
    __syncthreads();
    if (t < 512)
      rdL[t] = 32.f * bdL[t] + (gp[0][t] + gp[1][t]) * (1.f / 6400.f);
    __syncthreads();
    // ---- e for 196 pixels: 8-lane groups ----
    {
      int g = t & 7, grp = t >> 3;
#pragma unroll
      for (int r = 0; r < 2; ++r) {
        int p = r * 128 + grp;
        float acc = 0.f;
        if (p < 196) {
          const unsigned char* pp = preattL + p * 512;
#pragma unroll
          for (int i = 0; i < 8; ++i) {
            int c0 = i * 64 + g * 8;
            uint2 pv = *(const uint2*)(pp + c0);
#pragma unroll
            for (int jj = 0; jj < 4; ++jj) {
              float x0 = (float)((int)(pv.x << (24 - 8 * jj)) >> 24) + rdL[c0 + jj];
              float x1 = (float)((int)(pv.y << (24 - 8 * jj)) >> 24) + rdL[c0 + 4 + jj];
              acc += fmaxf(x0, 0.f) * rvL[c0 + jj] + fmaxf(x1, 0.f) * rvL[c0 + 4 + jj];
            }
          }
        }
        acc += __shfl_xor(acc, 1, 64);
        acc += __shfl_xor(acc, 2, 64);
        acc += __shfl_xor(acc, 4, 64);
        if (g == 0 && p < 196) eldL[p] = acc;
      }
    }
    __syncthreads();
    // ---- softmax ----
    if (t < 256) red1[t] = (t < 196) ? eldL[t] : -3.4e38f;
    __syncthreads();
    for (int st = 128; st > 0; st >>= 1) {
      if (t < st) red1[t] = fmaxf(red1[t], red1[t + st]);
      __syncthreads();
    }
    float mx = red1[0];
    __syncthreads();
    float ex = 0.f;
    if (t < 256) { ex = (t < 196) ? expf(eldL[t] - mx) : 0.f; red1[t] = ex; }
    __syncthreads();
    for (int st = 128; st > 0; st >>= 1) {
      if (t < st) red1[t] += red1[t + st];
      __syncthreads();
    }
    float ssum = red1[0];
    __syncthreads();
    // ---- alpha*beta -> int8 (dynamic scale), even/odd split; Saq = sum(q) ----
    float ab = 0.f;
    if (t < 256) {
      ab = (t < 196) ? ex * (beta / ssum) : 0.f;
      red1[t] = fabsf(ab);
    }
    __syncthreads();
    for (int st = 128; st > 0; st >>= 1) {
      if (t < st) red1[t] = fmaxf(red1[t], red1[t + st]);
      __syncthreads();
    }
    float sa = 127.f / fmaxf(red1[0], 1e-30f);
    int qa = 0;
    if (t < 196) {
      qa = (int)rintf(ab * sa);
      ((t & 1) ? aqO : aqE)[t >> 1] = (unsigned char)(qa & 0xff);
    }
    if (t < 256) red2[t] = (float)qa;
    __syncthreads();
    for (int st = 128; st > 0; st >>= 1) {
      if (t < st) red2[t] += red2[t + st];
      __syncthreads();
    }
    float Saq = red2[0];
    float inv_z = 1.f / (sa * 2.5f);
    __syncthreads();
    // ---- gate dots for slice col 512q+c, split by half ----
    {
      int cg = 512 * q + c;
      int az = 0, ah = 0;
      const unsigned char* ebase = E2T + (size_t)b * 229376 + (size_t)cg * 16;
      const uint4* ae = (const uint4*)aqE;
      const uint4* ao = (const uint4*)aqO;
      int i0 = half ? 4 : 0, i1 = half ? 7 : 4;
      for (int i = i0; i < i1; ++i) {
        uint4 wv = *(const uint4*)(ebase + (size_t)i * 32768);
        uint4 aev = ae[i], aov = ao[i];
        az = SDOT4(wv.x & 0x0F0F0F0Fu, aev.x, az);
        az = SDOT4((wv.x >> 4) & 0x0F0F0F0Fu, aov.x, az);
        az = SDOT4(wv.y & 0x0F0F0F0Fu, aev.y, az);
        az = SDOT4((wv.y >> 4) & 0x0F0F0F0Fu, aov.y, az);
        az = SDOT4(wv.z & 0x0F0F0F0Fu, aev.z, az);
        az = SDOT4((wv.z >> 4) & 0x0F0F0F0Fu, aov.z, az);
        az = SDOT4(wv.w & 0x0F0F0F0Fu, aev.w, az);
        az = SDOT4((wv.w >> 4) & 0x0F0F0F0Fu, aov.w, az);
      }
      const uint4* w0 = (const uint4*)(Whh4 + (size_t)cg * 256);
      const uint4* he = (const uint4*)hq_eo;
      const uint4* ho = (const uint4*)(hq_eo + 256);
#pragma unroll
      for (int i = 8 * half; i < 8 * half + 8; ++i) {
        uint4 wv = w0[i], hev = he[i], hov = ho[i];
        ah = SDOT4(wv.x & 0x0F0F0F0Fu, hev.x, ah);
        ah = SDOT4((wv.x >> 4) & 0x0F0F0F0Fu, hov.x, ah);
        ah = SDOT4(wv.y & 0x0F0F0F0Fu, hev.y, ah);
        ah = SDOT4((wv.y >> 4) & 0x0F0F0F0Fu, hov.y, ah);
        ah = SDOT4(wv.z & 0x0F0F0F0Fu, hev.z, ah);
        ah = SDOT4((wv.z >> 4) & 0x0F0F0F0Fu, hov.z, ah);
        ah = SDOT4(wv.w & 0x0F0F0F0Fu, hev.w, ah);
        ah = SDOT4((wv.w >> 4) & 0x0F0F0F0Fu, hov.w, ah);
      }
      gp[half][c] = (float)az * inv_z + (float)ah * (1.f / 15800.f);
    }
    __syncthreads();
    // ---- LSTM cell for j-slice [128q, 128q+128) ----
    if (t < 128) {
      int j = 128 * q + t;
      float corr = 8.f * Saq * inv_z + 8.f * Sh * (1.f / 15800.f);
      const float* gep = ge + ((size_t)(s * 64 + b)) * 2048;
      float gi = gp[0][4 * t + 0] + gp[1][4 * t + 0] - corr + gep[j];
      float gf = gp[0][4 * t + 1] + gp[1][4 * t + 1] - corr + gep[512 + j];
      float gg = gp[0][4 * t + 2] + gp[1][4 * t + 2] - corr + gep[1024 + j];
      float go = gp[0][4 * t + 3] + gp[1][4 * t + 3] - corr + gep[1536 + j];
      float si = 1.f / (1.f + expf(-gi));
      float sf = 1.f / (1.f + expf(-gf));
      float so = 1.f / (1.f + expf(-go));
      float cn = sf * creg + si * tanhf(gg);
      float hn = so * tanhf(cn);
      bool msk = s < dlb;
      float hnew = msk ? hn : hL[j];
      creg = msk ? cn : creg;
      ast_f(&hglob[((s + 1) & 1) * 32768 + b * 512 + j], hnew);
      // hall layout: [b*21 + s][512]  -> FC output rows are contiguous [b][t][v]
      hall[((size_t)b * 21 + s) * 512 + j] = f2bf(hn);
    }
    __syncthreads();  // drains vmcnt(0): hglob stores at IF$ before flag
    if (t == 0) ast_u(&flags[blk * 16], (unsigned)(s + 1));
  }
}

extern "C" void kernel_launch(void* const* d_in, const int* in_sizes, int n_in,
                              void* d_out, int out_size, void* d_ws, size_t ws_size,
                              hipStream_t stream) {
  (void)in_sizes; (void)n_in; (void)out_size; (void)ws_size;
  const float* enc = (const float*)d_in[0];
  const int* captions = (const int*)d_in[1];
  const int* cap_len = (const int*)d_in[2];
  const float* emb = (const float*)d_in[3];
  const float* We_att = (const float*)d_in[4];
  const float* be_att = (const float*)d_in[5];
  const float* Wd_att = (const float*)d_in[6];
  const float* bd_att = (const float*)d_in[7];
  const float* v_att = (const float*)d_in[8];
  const float* W_beta = (const float*)d_in[10];
  const float* b_beta = (const float*)d_in[11];
  const float* W_ih = (const float*)d_in[12];
  const float* b_ih = (const float*)d_in[13];
  const float* W_hh = (const float*)d_in[14];
  const float* b_hh = (const float*)d_in[15];
  const float* W_init_h = (const float*)d_in[16];
  const float* b_init_h = (const float*)d_in[17];
  const float* W_init_c = (const float*)d_in[18];
  const float* b_init_c = (const float*)d_in[19];
  const float* W_fc = (const float*)d_in[20];
  const float* b_fc = (const float*)d_in[21];

  float* out = (float*)d_out;
  float* out_pred = out;             // 64*21*32000
  float* out_caps = out + 43008000;  // 1408
  float* out_dlen = out + 43009408;  // 64
  float* out_alph = out + 43009472;  // 263424
  float* out_sind = out + 43272896;  // 64

  char* ws = (char*)d_ws;
  size_t off = 0;
  auto alloc = [&](size_t bytes) -> void* {
    off = (off + 255) & ~(size_t)255;
    void* p = ws + off;
    off += bytes;
    return p;
  };
  int* sind = (int*)alloc(64 * 4);
  int* dlen = (int*)alloc(64 * 4);
  int* emb_rows = (int*)alloc(1344 * 4);
  unsigned* flags = (unsigned*)alloc(256 * 16 * 4);
  unsigned short* enc_b = (unsigned short*)alloc((size_t)25690112 * 2);
  unsigned char* preatt8 = (unsigned char*)alloc((size_t)12544 * 512);
  unsigned char* E2T = (unsigned char*)alloc((size_t)64 * 229376);
  unsigned short* Wcomb = (unsigned short*)alloc((size_t)2560 * 2048 * 2);  // [WeattT;Wih2T]
  unsigned short* WihemT = (unsigned short*)alloc((size_t)2048 * 512 * 2);
  unsigned char* Whh4 = (unsigned char*)alloc((size_t)2048 * 256);
  unsigned short* WfcT = (unsigned short*)alloc((size_t)32000 * 512 * 2);
  unsigned short* WinitT = (unsigned short*)alloc((size_t)1024 * 2048 * 2);
  unsigned char* WdT8 = (unsigned char*)alloc((size_t)512 * 512);
  unsigned short* meanb = (unsigned short*)alloc((size_t)128 * 2048 * 2);
  float* binit = (float*)alloc(1024 * 4);
  unsigned short* Aemb_b = (unsigned short*)alloc((size_t)1408 * 512 * 2);
  unsigned short* hall_b = (unsigned short*)alloc((size_t)1408 * 512 * 2);
  float* ge = (float*)alloc((size_t)1408 * 2048 * 4);
  float* hc = (float*)alloc((size_t)128 * 1024 * 4);
  float* hglob = (float*)alloc((size_t)2 * 64 * 512 * 4);

  k_prep<<<1, 64, 0, stream>>>(cap_len, captions, sind, dlen, emb_rows, out_caps, out_dlen, out_sind);
  hipMemsetAsync(out_alph, 0, (size_t)263424 * 4, stream);
  hipMemsetAsync(flags, 0, 256 * 16 * 4, stream);
  hipMemsetAsync(meanb + (size_t)64 * 2048, 0, (size_t)64 * 2048 * 2, stream);

  k_gather_enc<<<12544, 256, 0, stream>>>(enc, sind, enc_b);
  k_tc8<<<dim3(8, 8), 256, 0, stream>>>(Wd_att, WdT8, 512, 512, 2048.f);
  // Wcomb rows 0..511 = We_att^T
  k_tc<<<dim3(8, 32), 256, 0, stream>>>(We_att, Wcomb, 2048, 512, 2048, 0, 0);
  // Wcomb rows 512..2559 = W_ih2^T (gate-interleave perm)
  k_tc<<<dim3(32, 32), 256, 0, stream>>>(W_ih + (size_t)512 * 2048, Wcomb + (size_t)512 * 2048,
                                         2048, 2048, 2048, 0, 2);
  k_tc<<<dim3(32, 8), 256, 0, stream>>>(W_ih, WihemT, 512, 2048, 512, 0, 0);
  k_w4<<<dim3(32, 8), 256, 0, stream>>>(W_hh, Whh4);
  k_tc<<<dim3(500, 8), 256, 0, stream>>>(W_fc, WfcT, 512, 32000, 512, 0, 0);
  k_tc<<<dim3(8, 32), 256, 0, stream>>>(W_init_h, WinitT, 2048, 512, 2048, 0, 0);
  k_tc<<<dim3(8, 32), 256, 0, stream>>>(W_init_c, WinitT + (size_t)512 * 2048, 2048, 512, 2048, 0, 0);
  k_biascat<<<4, 256, 0, stream>>>(b_init_h, b_init_c, binit);
  k_gather_emb<<<1408, 256, 0, stream>>>(emb, emb_rows, Aemb_b);
  k_meanb<<<dim3(64, 8), 256, 0, stream>>>(enc_b, meanb);

  // h0/c0: mean @ WinitT^T -> hc (M=128 pad, N=1024, K=2048)
  k_gemm<<<dim3(1, 8), 256, 0, stream>>>(meanb, WinitT, binit, nullptr, hc, nullptr, nullptr,
                                         128, 1024, 2048, 0, 64);
  k_h0g<<<128, 256, 0, stream>>>(hc, hglob);
  // ge = emb_seq @ W_ih[0:512] + b_ih + b_hh -> f32
  k_gemm<<<dim3(11, 16), 256, 0, stream>>>(Aemb_b, WihemT, b_ih, b_hh, ge, nullptr, nullptr,
                                           1408, 2048, 512, 0, 1344);
  // merged: [preatt | E2] = enc_s @ [WeattT ; Wih2T]^T  (N=2560, one A pass)
  k_gemm<<<dim3(98, 20), 256, 0, stream>>>(enc_b, Wcomb, be_att, nullptr, (float*)E2T,
                                           (unsigned short*)preatt8, nullptr, 12544, 2560, 2048,
                                           5, 12544);
  // the 21-step recurrence: 256 blocks (4 per batch), local sibling sync only
  k_loop<<<256, 1024, 0, stream>>>(preatt8, E2T, WdT8, Whh4, bd_att, v_att, W_beta, b_beta,
                                   ge, dlen, hc, hglob, hall_b, flags);
  // predictions = mask(h_all[b*21+t] @ W_fc + b_fc) -> contiguous [b][t][v]
  k_gemm<<<dim3(11, 250), 256, 0, stream>>>(hall_b, WfcT, b_fc, nullptr, out_pred, nullptr,
                                            dlen, 1408, 32000, 512, 2, 1344);
}